// Round 2
// baseline (901.593 us; speedup 1.0000x reference)
//
#include <hip/hip_runtime.h>
#include <stdint.h>

// NodeModel: edge MLP (Lin 128->64 + BN(batch stats) + SiLU) -> scatter_mean -> node MLP.
// Linear-split precompute + destination-sorted scatter:
//   P1 = x @ W1_top + b1  (bf16, [N,64])
//   sort: hist(col) -> exclusive scan -> perm (edges grouped by dest)
//   pass0: ea GEMM (K=64) + P1[row] -> column sum/sumsq            (unsorted, streaming)
//   pass1: ea[perm] GEMM + P1[row[perm]] -> norm+SiLU -> LDS segmented reduce
//          -> ~1 atomic per (dest-run, col) instead of per (edge, col)
//   P2 = x @ W2_top + b2
//   pass2/3: node GEMMs as before.
// Falls back to atomic scatter (and further to K=128 recompute) if ws too small.

#define EPS 1e-5f

using short8  = __attribute__((ext_vector_type(8))) short;
using floatx4 = __attribute__((ext_vector_type(4))) float;
using f32x4   = __attribute__((ext_vector_type(4))) float;

__device__ __forceinline__ ushort f2bf(float f) {
  uint32_t u = __builtin_bit_cast(uint32_t, f);
  u += 0x7fffu + ((u >> 16) & 1u);   // RNE
  return (ushort)(u >> 16);
}
__device__ __forceinline__ float bf2f(ushort u) {
  uint32_t x = ((uint32_t)u) << 16;
  return __builtin_bit_cast(float, x);
}
__device__ __forceinline__ float silu(float v) {
  return v / (1.0f + __expf(-v));
}
__device__ __forceinline__ void pack4(ushort* dst, f32x4 v) {
  uint2 p;
  p.x = (uint)f2bf(v.x) | ((uint)f2bf(v.y) << 16);
  p.y = (uint)f2bf(v.z) | ((uint)f2bf(v.w) << 16);
  *(uint2*)dst = p;
}

// ---------------- sort machinery ----------------

__global__ __launch_bounds__(256) void k_hist(const int* __restrict__ col,
                                              int* __restrict__ hist, int E) {
  const int stride = gridDim.x * 256;
  for (int e = blockIdx.x * 256 + threadIdx.x; e < E; e += stride)
    atomicAdd(&hist[col[e]], 1);
}

// per-block (2048 elems) sums of hist -> bsum[b]
__global__ __launch_bounds__(256) void k_scanA(const int* __restrict__ hist,
                                               int* __restrict__ bsum, int n) {
  __shared__ int sd[256];
  const int tid = threadIdx.x;
  const int base = blockIdx.x * 2048 + tid * 8;
  int s = 0;
#pragma unroll
  for (int j = 0; j < 8; ++j) {
    const int i = base + j;
    if (i < n) s += hist[i];
  }
  sd[tid] = s;
  __syncthreads();
  for (int off = 128; off > 0; off >>= 1) {
    if (tid < off) sd[tid] += sd[tid + off];
    __syncthreads();
  }
  if (tid == 0) bsum[blockIdx.x] = sd[0];
}

// in-place exclusive scan of bsum (nb entries), 1 block of 64 threads
__global__ void k_scanB(int* __restrict__ bsum, int nb) {
  const int lane = threadIdx.x;
  int base = 0;
  for (int c = 0; c < nb; c += 64) {
    const int t = c + lane;
    int v = (t < nb) ? bsum[t] : 0;
    const int orig = v;
#pragma unroll
    for (int off = 1; off < 64; off <<= 1) {
      const int u = __shfl_up(v, off);
      if (lane >= off) v += u;
    }
    if (t < nb) bsum[t] = base + v - orig;   // exclusive
    base += __shfl(v, 63);
  }
}

// block-local exclusive scan + bscan offset -> cursor (= offsets); also cntf = (float)hist
__global__ __launch_bounds__(256) void k_scanC(const int* __restrict__ hist,
                                               const int* __restrict__ bscan,
                                               int* __restrict__ cursor,
                                               float* __restrict__ cntf, int n) {
  __shared__ int sd[256];
  const int tid = threadIdx.x;
  const int base = blockIdx.x * 2048 + tid * 8;
  int loc[8];
  int s = 0;
#pragma unroll
  for (int j = 0; j < 8; ++j) {
    const int i = base + j;
    loc[j] = s;
    if (i < n) s += hist[i];
  }
  const int own = s;
  sd[tid] = s;
  __syncthreads();
  for (int off = 1; off < 256; off <<= 1) {
    const int v = (tid >= off) ? sd[tid - off] : 0;
    __syncthreads();
    sd[tid] += v;
    __syncthreads();
  }
  const int add = bscan[blockIdx.x] + sd[tid] - own;
#pragma unroll
  for (int j = 0; j < 8; ++j) {
    const int i = base + j;
    if (i < n) {
      cursor[i] = add + loc[j];
      cntf[i] = (float)hist[i];
    }
  }
}

__global__ __launch_bounds__(256) void k_scatter(const int* __restrict__ col,
                                                 int* __restrict__ cursor,
                                                 int* __restrict__ perm, int E) {
  const int stride = gridDim.x * 256;
  for (int e = blockIdx.x * 256 + threadIdx.x; e < E; e += stride) {
    const int d = col[e];
    const int pos = atomicAdd(&cursor[d], 1);
    perm[pos] = e;
  }
}

// ---------------- P precompute ----------------

// P = x @ W_top + bias, stored bf16. W is [128,64] row-major; top = rows 0..63.
__global__ __launch_bounds__(256) void precompute_P(
    const float* __restrict__ x, const float* __restrict__ W,
    const float* __restrict__ bias, ushort* __restrict__ P,
    int nrows, int ntiles) {
  __shared__ __align__(16) ushort Xls[64 * 72];
  __shared__ __align__(16) ushort Wts[64 * 72];
  __shared__ float biasl[64];

  const int tid  = threadIdx.x;
  const int lane = tid & 63;
  const int wv   = tid >> 6;
  const int m    = lane & 15;
  const int quad = lane >> 4;

  for (int i = tid; i < 64 * 64; i += 256) {
    const int n = i >> 6, k = i & 63;
    Wts[n * 72 + k] = f2bf(W[k * 64 + n]);
  }
  if (tid < 64) biasl[tid] = bias[tid];

  for (int t = blockIdx.x; t < ntiles; t += gridDim.x) {
    __syncthreads();
    const int base = t * 64;
    for (int i = tid; i < 1024; i += 256) {
      const int e = i >> 4;
      const int c4 = (i & 15) << 2;
      const int grow = base + e;
      f32x4 v = {0.f, 0.f, 0.f, 0.f};
      if (grow < nrows) v = *(const f32x4*)(x + (size_t)grow * 64 + c4);
      pack4(&Xls[e * 72 + c4], v);
    }
    __syncthreads();

    floatx4 acc[4];
#pragma unroll
    for (int nt = 0; nt < 4; ++nt) acc[nt] = (floatx4){0.f, 0.f, 0.f, 0.f};
    const ushort* arow = &Xls[(wv * 16 + m) * 72];
#pragma unroll
    for (int kc = 0; kc < 2; ++kc) {
      const short8 af = *(const short8*)(arow + kc * 32 + quad * 8);
#pragma unroll
      for (int nt = 0; nt < 4; ++nt) {
        const short8 bfr = *(const short8*)(&Wts[(nt * 16 + m) * 72 + kc * 32 + quad * 8]);
        acc[nt] = __builtin_amdgcn_mfma_f32_16x16x32_bf16(af, bfr, acc[nt], 0, 0, 0);
      }
    }
    const int lr0 = wv * 16 + quad * 4;
#pragma unroll
    for (int nt = 0; nt < 4; ++nt) {
      const int c = nt * 16 + m;
      const float bb = biasl[c];
#pragma unroll
      for (int r = 0; r < 4; ++r) {
        const int grow = base + lr0 + r;
        if (grow < nrows) P[(size_t)grow * 64 + c] = f2bf(acc[nt][r] + bb);
      }
    }
  }
}

// ---------------- sorted edge scatter (pass1) ----------------

__global__ __launch_bounds__(256) void edge_pass1_sorted(
    const float* __restrict__ ea, const int* __restrict__ rowidx,
    const int* __restrict__ colidx, const int* __restrict__ perm,
    const float* __restrict__ W, const float* __restrict__ scsh,
    const ushort* __restrict__ Pbf, float* __restrict__ sums_out,
    int nrows, int ntiles) {
  __shared__ __align__(16) ushort Albs[64 * 72];
  __shared__ __align__(16) ushort Btl[64 * 72];
  __shared__ float Ol[64][66];
  __shared__ float scl[128];
  __shared__ int dest_l[64];

  const int tid  = threadIdx.x;
  const int lane = tid & 63;
  const int wv   = tid >> 6;
  const int m    = lane & 15;
  const int quad = lane >> 4;

  for (int i = tid; i < 64 * 64; i += 256) {
    const int n = i >> 6, k = i & 63;
    Btl[n * 72 + k] = f2bf(W[(64 + k) * 64 + n]);
  }
  if (tid < 128) scl[tid] = scsh[tid];

  for (int t = blockIdx.x; t < ntiles; t += gridDim.x) {
    __syncthreads();  // guards Albs/Ol/dest_l reuse
    const int base = t * 64;

    // P fragments for this wave's output rows (double indirection via perm)
    float pv[4][4];
#pragma unroll
    for (int r = 0; r < 4; ++r) {
      const int grow = base + wv * 16 + quad * 4 + r;
      float p0 = 0.f, p1 = 0.f, p2 = 0.f, p3 = 0.f;
      if (grow < nrows) {
        const int prow = rowidx[perm[grow]];
        const ushort* pp = Pbf + (size_t)prow * 64 + m;
        p0 = bf2f(pp[0]);  p1 = bf2f(pp[16]);
        p2 = bf2f(pp[32]); p3 = bf2f(pp[48]);
      }
      pv[0][r] = p0; pv[1][r] = p1; pv[2][r] = p2; pv[3][r] = p3;
    }
    if (tid < 64) {
      const int grow = base + tid;
      dest_l[tid] = (grow < nrows) ? colidx[perm[grow]] : -1;
    }
    // A staging: gather ea rows in sorted order (256B contiguous per row)
    for (int i = tid; i < 1024; i += 256) {
      const int e  = i >> 4;
      const int c4 = (i & 15) << 2;
      const int grow = base + e;
      f32x4 v = {0.f, 0.f, 0.f, 0.f};
      if (grow < nrows)
        v = __builtin_nontemporal_load((const f32x4*)(ea + (size_t)perm[grow] * 64 + c4));
      pack4(&Albs[e * 72 + c4], v);
    }
    __syncthreads();

    floatx4 acc[4];
#pragma unroll
    for (int nt = 0; nt < 4; ++nt) acc[nt] = (floatx4){0.f, 0.f, 0.f, 0.f};
    const ushort* arow = &Albs[(wv * 16 + m) * 72];
#pragma unroll
    for (int kc = 0; kc < 2; ++kc) {
      const short8 af = *(const short8*)(arow + kc * 32 + quad * 8);
#pragma unroll
      for (int nt = 0; nt < 4; ++nt) {
        const short8 bfr = *(const short8*)(&Btl[(nt * 16 + m) * 72 + kc * 32 + quad * 8]);
        acc[nt] = __builtin_amdgcn_mfma_f32_16x16x32_bf16(af, bfr, acc[nt], 0, 0, 0);
      }
    }

    // epilogue: SiLU -> LDS tile (cols nt*16+m, rows quad*4+r)
    const int lr0 = wv * 16 + quad * 4;
#pragma unroll
    for (int nt = 0; nt < 4; ++nt) {
      const int c = nt * 16 + m;
      const float sc = scl[c];
      const float sh = scl[64 + c];
#pragma unroll
      for (int r = 0; r < 4; ++r) {
        const float h = acc[nt][r] + pv[nt][r];
        Ol[lr0 + r][c] = silu(h * sc + sh);
      }
    }
    __syncthreads();

    // segmented reduce: 4 threads per column, 16 rows each; runs are
    // wave-uniform (all lanes share the dest sequence) -> coalesced atomics
    {
      const int c  = tid & 63;
      const int r0 = (tid >> 6) * 16;
      float a = 0.f;
      int cur = -1;
#pragma unroll
      for (int i = 0; i < 16; ++i) {
        const int d = dest_l[r0 + i];
        if (d != cur) {
          if (cur >= 0) unsafeAtomicAdd(&sums_out[(size_t)cur * 64 + c], a);
          cur = d;
          a = 0.f;
        }
        if (d >= 0) a += Ol[r0 + i][c];
      }
      if (cur >= 0) unsafeAtomicAdd(&sums_out[(size_t)cur * 64 + c], a);
    }
  }
}

// ---------------- fused GEMM (modes 0,2,3 + fallback mode 1) ----------------

// MODE: 0 = edge stats, 1 = edge scatter (fallback), 2 = node stats, 3 = node out
// USEP: 1 = K=64 GEMM + P-fragment accumulator init; 0 = legacy K=128 recompute
template <int MODE, int USEP>
__global__ __launch_bounds__(256) void fused_gemm(
    const float* __restrict__ x, const float* __restrict__ ea,
    const float* __restrict__ sums_in, const float* __restrict__ cnt,
    const int* __restrict__ rowidx, const int* __restrict__ colidx,
    const float* __restrict__ W, const float* __restrict__ bias,
    const float* __restrict__ scsh, const ushort* __restrict__ Pbf,
    float* __restrict__ ssum, float* __restrict__ ssq,
    float* __restrict__ sums_out, float* __restrict__ cnt_out,
    float* __restrict__ out,
    float* __restrict__ zbuf, int zn,
    int nrows, int ntiles) {
  constexpr int KC = USEP ? 64 : 128;
  constexpr int KP = USEP ? 72 : 136;
  constexpr int CH = KC / 4;
  __shared__ __align__(16) ushort Albs[64 * KP];
  __shared__ __align__(16) ushort Btl[64 * KP];
  __shared__ float wsum[4][64];
  __shared__ float wsq[4][64];
  __shared__ float biasl[64];
  __shared__ float scl[128];
  __shared__ int coltile[64];

  const int tid  = threadIdx.x;
  const int lane = tid & 63;
  const int wv   = tid >> 6;
  const int m    = lane & 15;
  const int quad = lane >> 4;

  if (MODE == 0 && zbuf) {
    const int stride = gridDim.x * 256;
    const f32x4 z = {0.f, 0.f, 0.f, 0.f};
    for (int i = blockIdx.x * 256 + tid; i < (zn >> 2); i += stride)
      ((f32x4*)zbuf)[i] = z;
    if (blockIdx.x == 0 && tid < (zn & 3)) zbuf[(zn & ~3) + tid] = 0.f;
  }

  for (int i = tid; i < 64 * KC; i += 256) {
    const int n = i / KC, k = i % KC;
    const int gk = USEP ? (64 + k) : k;
    Btl[n * KP + k] = f2bf(W[gk * 64 + n]);
  }
  if (!USEP) { if (tid < 64) biasl[tid] = bias[tid]; }
  if (MODE == 1 || MODE == 3) {
    if (tid < 128) scl[tid] = scsh[tid];
  }
  if (MODE == 0 || MODE == 2) {
    wsum[wv][lane] = 0.f;
    wsq[wv][lane]  = 0.f;
  }

  for (int t = blockIdx.x; t < ntiles; t += gridDim.x) {
    __syncthreads();
    const int base = t * 64;

    float pv[4][4];
    if (USEP) {
#pragma unroll
      for (int r = 0; r < 4; ++r) {
        const int grow = base + wv * 16 + quad * 4 + r;
        float p0 = 0.f, p1 = 0.f, p2 = 0.f, p3 = 0.f;
        if (grow < nrows) {
          const int prow = (MODE <= 1) ? rowidx[grow] : grow;
          const ushort* pp = Pbf + (size_t)prow * 64 + m;
          p0 = bf2f(pp[0]);  p1 = bf2f(pp[16]);
          p2 = bf2f(pp[32]); p3 = bf2f(pp[48]);
        }
        pv[0][r] = p0; pv[1][r] = p1; pv[2][r] = p2; pv[3][r] = p3;
      }
    }

    for (int i = tid; i < 64 * CH; i += 256) {
      const int e  = i / CH;
      const int c4 = (i % CH) << 2;
      const int grow = base + e;
      f32x4 v = {0.f, 0.f, 0.f, 0.f};
      if (grow < nrows) {
        if (USEP) {
          if (MODE <= 1) {
            v = __builtin_nontemporal_load((const f32x4*)(ea + (size_t)grow * 64 + c4));
            if (MODE == 1 && c4 == 0) coltile[e] = colidx[grow];
          } else {
            const float inv = 1.0f / fmaxf(cnt[grow], 1.0f);
            v = *(const f32x4*)(sums_in + (size_t)grow * 64 + c4);
            v *= inv;
          }
        } else {
          if (MODE <= 1) {
            if (c4 < 64) {
              const int r = rowidx[grow];
              v = *(const f32x4*)(x + (size_t)r * 64 + c4);
            } else {
              v = __builtin_nontemporal_load((const f32x4*)(ea + (size_t)grow * 64 + (c4 - 64)));
            }
            if (MODE == 1 && c4 == 0) coltile[e] = colidx[grow];
          } else {
            if (c4 < 64) {
              v = *(const f32x4*)(x + (size_t)grow * 64 + c4);
            } else {
              const float inv = 1.0f / fmaxf(cnt[grow], 1.0f);
              v = *(const f32x4*)(sums_in + (size_t)grow * 64 + (c4 - 64));
              v *= inv;
            }
          }
        }
      }
      pack4(&Albs[e * KP + c4], v);
    }
    __syncthreads();

    floatx4 acc[4];
#pragma unroll
    for (int nt = 0; nt < 4; ++nt) acc[nt] = (floatx4){0.f, 0.f, 0.f, 0.f};
    const ushort* arow = &Albs[(wv * 16 + m) * KP];
#pragma unroll
    for (int kc = 0; kc < KC / 32; ++kc) {
      const short8 af = *(const short8*)(arow + kc * 32 + quad * 8);
#pragma unroll
      for (int nt = 0; nt < 4; ++nt) {
        const short8 bfr = *(const short8*)(&Btl[(nt * 16 + m) * KP + kc * 32 + quad * 8]);
        acc[nt] = __builtin_amdgcn_mfma_f32_16x16x32_bf16(af, bfr, acc[nt], 0, 0, 0);
      }
    }

    const int lr0 = wv * 16 + quad * 4;
#pragma unroll
    for (int nt = 0; nt < 4; ++nt) {
      const int c = nt * 16 + m;
      const float bb = USEP ? 0.f : biasl[c];
      if (MODE == 0 || MODE == 2) {
        float s = 0.f, q = 0.f;
#pragma unroll
        for (int r = 0; r < 4; ++r) {
          const int grow = base + lr0 + r;
          if (grow < nrows) {
            const float v = acc[nt][r] + (USEP ? pv[nt][r] : bb);
            s += v;
            q += v * v;
          }
        }
        s += __shfl_xor(s, 16); s += __shfl_xor(s, 32);
        q += __shfl_xor(q, 16); q += __shfl_xor(q, 32);
        if (quad == 0) { wsum[wv][c] += s; wsq[wv][c] += q; }
      } else {
        const float sc = scl[c];
        const float sh = scl[64 + c];
#pragma unroll
        for (int r = 0; r < 4; ++r) {
          const int e = lr0 + r;
          const int grow = base + e;
          if (grow < nrows) {
            const float h = acc[nt][r] + (USEP ? pv[nt][r] : bb);
            const float o = silu(h * sc + sh);
            if (MODE == 1) {
              unsafeAtomicAdd(&sums_out[(size_t)coltile[e] * 64 + c], o);
            } else {
              __builtin_nontemporal_store(o, &out[(size_t)grow * 64 + c]);
            }
          }
        }
        if (MODE == 1 && nt == 0 && m == 0) {
#pragma unroll
          for (int r = 0; r < 4; ++r) {
            const int e = lr0 + r;
            if (base + e < nrows) unsafeAtomicAdd(&cnt_out[coltile[e]], 1.0f);
          }
        }
      }
    }
  }

  if (MODE == 0 || MODE == 2) {
    __syncthreads();
    if (tid < 128) {
      const int c = tid & 63;
      if (tid < 64) {
        unsafeAtomicAdd(&ssum[c], wsum[0][c] + wsum[1][c] + wsum[2][c] + wsum[3][c]);
      } else {
        unsafeAtomicAdd(&ssq[c], wsq[0][c] + wsq[1][c] + wsq[2][c] + wsq[3][c]);
      }
    }
  }
}

__global__ void finalize_stats(const float* __restrict__ ss, const float* __restrict__ sq,
                               const float* __restrict__ g, const float* __restrict__ be,
                               float* __restrict__ scsh, float invn) {
  const int c = threadIdx.x;  // 64 threads
  const float mu  = ss[c] * invn;
  const float var = sq[c] * invn - mu * mu;
  const float rs  = rsqrtf(fmaxf(var, 0.0f) + EPS);
  const float s   = g[c] * rs;
  scsh[c]      = s;
  scsh[64 + c] = be[c] - mu * s;
}

extern "C" void kernel_launch(void* const* d_in, const int* in_sizes, int n_in,
                              void* d_out, int out_size, void* d_ws, size_t ws_size,
                              hipStream_t stream) {
  const int N = in_sizes[0] / 64;
  const int E = in_sizes[1] / 64;
  const float* x   = (const float*)d_in[0];
  const float* ea  = (const float*)d_in[1];
  const float* W1  = (const float*)d_in[3];
  const float* b1  = (const float*)d_in[4];
  const float* g1  = (const float*)d_in[5];
  const float* be1 = (const float*)d_in[6];
  const float* W2  = (const float*)d_in[7];
  const float* b2  = (const float*)d_in[8];
  const float* g2  = (const float*)d_in[9];
  const float* be2 = (const float*)d_in[10];
  const int* ei   = (const int*)d_in[11];  // [2,E] int32
  const int* row  = ei;
  const int* colv = ei + E;

  const int ntE = (E + 63) / 64;
  const int ntN = (N + 63) / 64;
  const int gE  = ntE < 2048 ? ntE : 2048;
  const int gN  = ntN < 2048 ? ntN : 2048;
  const int nb  = (N + 2047) / 2048;

  // Sorted-path layout (4B words):
  //   sums N*64 | cntf N | statE 128 | statN 128 | scsh1 128 | scsh2 128 |
  //   hist N | cursor N | bsum 2048 | perm E | Pbf N*32
  const size_t wSort = (size_t)N * 99 + (size_t)E + 2560 + 512;
  const size_t needSort = wSort * sizeof(float);
  // Old-path layout: sums N*64 | cnt N | stats/scsh 512 | Pbf N*32
  const size_t needP = ((size_t)N * 97 + 512) * sizeof(float);

  if (ws_size >= needSort) {
    float* sums  = (float*)d_ws;
    float* cntf  = sums + (size_t)N * 64;
    float* statE = cntf + N;
    float* statN = statE + 128;
    float* scsh1 = statN + 128;
    float* scsh2 = scsh1 + 128;
    int*   hist  = (int*)(scsh2 + 128);
    int*   curs  = hist + N;
    int*   bsum  = curs + N;
    int*   perm  = bsum + 2048;
    ushort* Pbf  = (ushort*)(perm + E);

    // statE..scsh2 (512 floats) + hist (N ints) are contiguous
    hipMemsetAsync(statE, 0, (512 + (size_t)N) * sizeof(float), stream);

    k_hist<<<dim3(1024), dim3(256), 0, stream>>>(colv, hist, E);
    k_scanA<<<dim3(nb), dim3(256), 0, stream>>>(hist, bsum, N);
    k_scanB<<<dim3(1), dim3(64), 0, stream>>>(bsum, nb);
    k_scanC<<<dim3(nb), dim3(256), 0, stream>>>(hist, bsum, curs, cntf, N);
    k_scatter<<<dim3(1024), dim3(256), 0, stream>>>(colv, curs, perm, E);

    precompute_P<<<dim3(gN), dim3(256), 0, stream>>>(x, W1, b1, Pbf, N, ntN);
    fused_gemm<0, 1><<<dim3(gE), dim3(256), 0, stream>>>(
        x, ea, nullptr, nullptr, row, nullptr, W1, b1, nullptr, Pbf,
        statE, statE + 64, nullptr, nullptr, nullptr, sums, N * 64, E, ntE);
    finalize_stats<<<dim3(1), dim3(64), 0, stream>>>(statE, statE + 64, g1, be1, scsh1,
                                                     1.0f / (float)E);
    edge_pass1_sorted<<<dim3(gE), dim3(256), 0, stream>>>(
        ea, row, colv, perm, W1, scsh1, Pbf, sums, E, ntE);
    precompute_P<<<dim3(gN), dim3(256), 0, stream>>>(x, W2, b2, Pbf, N, ntN);
    fused_gemm<2, 1><<<dim3(gN), dim3(256), 0, stream>>>(
        x, nullptr, sums, cntf, nullptr, nullptr, W2, b2, nullptr, Pbf,
        statN, statN + 64, nullptr, nullptr, nullptr, nullptr, 0, N, ntN);
    finalize_stats<<<dim3(1), dim3(64), 0, stream>>>(statN, statN + 64, g2, be2, scsh2,
                                                     1.0f / (float)N);
    fused_gemm<3, 1><<<dim3(gN), dim3(256), 0, stream>>>(
        x, nullptr, sums, cntf, nullptr, nullptr, W2, b2, scsh2, Pbf,
        nullptr, nullptr, nullptr, nullptr, (float*)d_out, nullptr, 0, N, ntN);
    return;
  }

  // -------- fallback paths (previous design) --------
  float* sums  = (float*)d_ws;
  float* cnt   = sums + (size_t)N * 64;
  float* statE = cnt + N;
  float* statN = statE + 128;
  float* scsh1 = statN + 128;
  float* scsh2 = scsh1 + 128;
  ushort* Pbf  = (ushort*)(scsh2 + 128);
  const bool useP = (ws_size >= needP);
  const int zn = N * 65;

  hipMemsetAsync(statE, 0, 512 * sizeof(float), stream);

  if (useP) {
    precompute_P<<<dim3(gN), dim3(256), 0, stream>>>(x, W1, b1, Pbf, N, ntN);
    fused_gemm<0, 1><<<dim3(gE), dim3(256), 0, stream>>>(
        x, ea, nullptr, nullptr, row, nullptr, W1, b1, nullptr, Pbf,
        statE, statE + 64, nullptr, nullptr, nullptr, sums, zn, E, ntE);
    finalize_stats<<<dim3(1), dim3(64), 0, stream>>>(statE, statE + 64, g1, be1, scsh1,
                                                     1.0f / (float)E);
    fused_gemm<1, 1><<<dim3(gE), dim3(256), 0, stream>>>(
        x, ea, nullptr, nullptr, row, colv, W1, b1, scsh1, Pbf,
        nullptr, nullptr, sums, cnt, nullptr, nullptr, 0, E, ntE);
    precompute_P<<<dim3(gN), dim3(256), 0, stream>>>(x, W2, b2, Pbf, N, ntN);
    fused_gemm<2, 1><<<dim3(gN), dim3(256), 0, stream>>>(
        x, nullptr, sums, cnt, nullptr, nullptr, W2, b2, nullptr, Pbf,
        statN, statN + 64, nullptr, nullptr, nullptr, nullptr, 0, N, ntN);
    finalize_stats<<<dim3(1), dim3(64), 0, stream>>>(statN, statN + 64, g2, be2, scsh2,
                                                     1.0f / (float)N);
    fused_gemm<3, 1><<<dim3(gN), dim3(256), 0, stream>>>(
        x, nullptr, sums, cnt, nullptr, nullptr, W2, b2, scsh2, Pbf,
        nullptr, nullptr, nullptr, nullptr, (float*)d_out, nullptr, 0, N, ntN);
  } else {
    fused_gemm<0, 0><<<dim3(gE), dim3(256), 0, stream>>>(
        x, ea, nullptr, nullptr, row, nullptr, W1, b1, nullptr, nullptr,
        statE, statE + 64, nullptr, nullptr, nullptr, sums, zn, E, ntE);
    finalize_stats<<<dim3(1), dim3(64), 0, stream>>>(statE, statE + 64, g1, be1, scsh1,
                                                     1.0f / (float)E);
    fused_gemm<1, 0><<<dim3(gE), dim3(256), 0, stream>>>(
        x, ea, nullptr, nullptr, row, colv, W1, b1, scsh1, nullptr,
        nullptr, nullptr, sums, cnt, nullptr, nullptr, 0, E, ntE);
    fused_gemm<2, 0><<<dim3(gN), dim3(256), 0, stream>>>(
        x, nullptr, sums, cnt, nullptr, nullptr, W2, b2, nullptr, nullptr,
        statN, statN + 64, nullptr, nullptr, nullptr, nullptr, 0, N, ntN);
    finalize_stats<<<dim3(1), dim3(64), 0, stream>>>(statN, statN + 64, g2, be2, scsh2,
                                                     1.0f / (float)N);
    fused_gemm<3, 0><<<dim3(gN), dim3(256), 0, stream>>>(
        x, nullptr, sums, cnt, nullptr, nullptr, W2, b2, scsh2, nullptr,
        nullptr, nullptr, nullptr, nullptr, (float*)d_out, nullptr, 0, N, ntN);
  }
}

// Round 3
// 753.878 us; speedup vs baseline: 1.1959x; 1.1959x over previous
//
#include <hip/hip_runtime.h>
#include <hip/hip_fp16.h>
#include <stdint.h>

// NodeModel: edge MLP (Lin 128->64 + BN(batch stats) + SiLU) -> scatter_mean -> node MLP.
// Scatter-on-write / stream-on-read design:
//   P1 = x @ W1_top + b1  (bf16, [N,64])
//   sort: hist(col) -> scan -> inv[e] = sorted position of edge e
//   pass0: stream ea, GEMM K=64 + P1[row] -> stats AND h1 (f16) scattered to h1s[inv[e]]
//   seg_reduce_dest: stream h1s (sorted), norm+SiLU, per-dest mean -> agg (NO atomics)
//   P2 = x @ W2_top + b2
//   pass2/3: node GEMMs on [x | agg].
// Fallbacks: R2 sorted-gather path -> P path -> legacy K=128 path if ws too small.

#define EPS 1e-5f

using short8  = __attribute__((ext_vector_type(8))) short;
using floatx4 = __attribute__((ext_vector_type(4))) float;
using f32x4   = __attribute__((ext_vector_type(4))) float;

__device__ __forceinline__ ushort f2bf(float f) {
  uint32_t u = __builtin_bit_cast(uint32_t, f);
  u += 0x7fffu + ((u >> 16) & 1u);   // RNE
  return (ushort)(u >> 16);
}
__device__ __forceinline__ float bf2f(ushort u) {
  uint32_t x = ((uint32_t)u) << 16;
  return __builtin_bit_cast(float, x);
}
__device__ __forceinline__ ushort f2h(float f) {
  __half h = __float2half(f);   // RNE
  return *reinterpret_cast<ushort*>(&h);
}
__device__ __forceinline__ float h2f(ushort u) {
  __half h;
  *reinterpret_cast<ushort*>(&h) = u;
  return __half2float(h);
}
__device__ __forceinline__ float silu(float v) {
  return v / (1.0f + __expf(-v));
}
__device__ __forceinline__ void pack4(ushort* dst, f32x4 v) {
  uint2 p;
  p.x = (uint)f2bf(v.x) | ((uint)f2bf(v.y) << 16);
  p.y = (uint)f2bf(v.z) | ((uint)f2bf(v.w) << 16);
  *(uint2*)dst = p;
}

// ---------------- sort machinery ----------------

__global__ __launch_bounds__(256) void k_hist(const int* __restrict__ col,
                                              int* __restrict__ hist, int E) {
  const int stride = gridDim.x * 256;
  for (int e = blockIdx.x * 256 + threadIdx.x; e < E; e += stride)
    atomicAdd(&hist[col[e]], 1);
}

__global__ __launch_bounds__(256) void k_scanA(const int* __restrict__ hist,
                                               int* __restrict__ bsum, int n) {
  __shared__ int sd[256];
  const int tid = threadIdx.x;
  const int base = blockIdx.x * 2048 + tid * 8;
  int s = 0;
#pragma unroll
  for (int j = 0; j < 8; ++j) {
    const int i = base + j;
    if (i < n) s += hist[i];
  }
  sd[tid] = s;
  __syncthreads();
  for (int off = 128; off > 0; off >>= 1) {
    if (tid < off) sd[tid] += sd[tid + off];
    __syncthreads();
  }
  if (tid == 0) bsum[blockIdx.x] = sd[0];
}

__global__ void k_scanB(int* __restrict__ bsum, int nb) {
  const int lane = threadIdx.x;
  int base = 0;
  for (int c = 0; c < nb; c += 64) {
    const int t = c + lane;
    int v = (t < nb) ? bsum[t] : 0;
    const int orig = v;
#pragma unroll
    for (int off = 1; off < 64; off <<= 1) {
      const int u = __shfl_up(v, off);
      if (lane >= off) v += u;
    }
    if (t < nb) bsum[t] = base + v - orig;   // exclusive
    base += __shfl(v, 63);
  }
}

__global__ __launch_bounds__(256) void k_scanC(const int* __restrict__ hist,
                                               const int* __restrict__ bscan,
                                               int* __restrict__ cursor,
                                               float* __restrict__ cntf, int n) {
  __shared__ int sd[256];
  const int tid = threadIdx.x;
  const int base = blockIdx.x * 2048 + tid * 8;
  int loc[8];
  int s = 0;
#pragma unroll
  for (int j = 0; j < 8; ++j) {
    const int i = base + j;
    loc[j] = s;
    if (i < n) s += hist[i];
  }
  const int own = s;
  sd[tid] = s;
  __syncthreads();
  for (int off = 1; off < 256; off <<= 1) {
    const int v = (tid >= off) ? sd[tid - off] : 0;
    __syncthreads();
    sd[tid] += v;
    __syncthreads();
  }
  const int add = bscan[blockIdx.x] + sd[tid] - own;
#pragma unroll
  for (int j = 0; j < 8; ++j) {
    const int i = base + j;
    if (i < n) {
      cursor[i] = add + loc[j];
      if (cntf) cntf[i] = (float)hist[i];
    }
  }
}

// pos = sorted position of edge e. perm[pos]=e (fallback path), inv[e]=pos (top path).
__global__ __launch_bounds__(256) void k_scatter(const int* __restrict__ col,
                                                 int* __restrict__ cursor,
                                                 int* __restrict__ perm,
                                                 int* __restrict__ inv, int E) {
  const int stride = gridDim.x * 256;
  for (int e = blockIdx.x * 256 + threadIdx.x; e < E; e += stride) {
    const int d = col[e];
    const int pos = atomicAdd(&cursor[d], 1);
    if (perm) perm[pos] = e;
    if (inv) inv[e] = pos;
  }
}

// ---------------- P precompute ----------------

// P = x @ W_top + bias, stored bf16. W is [128,64] row-major; top = rows 0..63.
__global__ __launch_bounds__(256) void precompute_P(
    const float* __restrict__ x, const float* __restrict__ W,
    const float* __restrict__ bias, ushort* __restrict__ P,
    int nrows, int ntiles) {
  __shared__ __align__(16) ushort Xls[64 * 72];
  __shared__ __align__(16) ushort Wts[64 * 72];
  __shared__ float biasl[64];

  const int tid  = threadIdx.x;
  const int lane = tid & 63;
  const int wv   = tid >> 6;
  const int m    = lane & 15;
  const int quad = lane >> 4;

  for (int i = tid; i < 64 * 64; i += 256) {
    const int n = i >> 6, k = i & 63;
    Wts[n * 72 + k] = f2bf(W[k * 64 + n]);
  }
  if (tid < 64) biasl[tid] = bias[tid];
  __syncthreads();
  short8 breg[2][4];   // B fragments are tile-invariant: keep in registers
#pragma unroll
  for (int kc = 0; kc < 2; ++kc)
#pragma unroll
    for (int nt = 0; nt < 4; ++nt)
      breg[kc][nt] = *(const short8*)(&Wts[(nt * 16 + m) * 72 + kc * 32 + quad * 8]);

  for (int t = blockIdx.x; t < ntiles; t += gridDim.x) {
    __syncthreads();
    const int base = t * 64;
    for (int i = tid; i < 1024; i += 256) {
      const int e = i >> 4;
      const int c4 = (i & 15) << 2;
      const int grow = base + e;
      f32x4 v = {0.f, 0.f, 0.f, 0.f};
      if (grow < nrows) v = *(const f32x4*)(x + (size_t)grow * 64 + c4);
      pack4(&Xls[e * 72 + c4], v);
    }
    __syncthreads();

    floatx4 acc[4];
#pragma unroll
    for (int nt = 0; nt < 4; ++nt) acc[nt] = (floatx4){0.f, 0.f, 0.f, 0.f};
    const ushort* arow = &Xls[(wv * 16 + m) * 72];
#pragma unroll
    for (int kc = 0; kc < 2; ++kc) {
      const short8 af = *(const short8*)(arow + kc * 32 + quad * 8);
#pragma unroll
      for (int nt = 0; nt < 4; ++nt)
        acc[nt] = __builtin_amdgcn_mfma_f32_16x16x32_bf16(af, breg[kc][nt], acc[nt], 0, 0, 0);
    }
    const int lr0 = wv * 16 + quad * 4;
#pragma unroll
    for (int nt = 0; nt < 4; ++nt) {
      const int c = nt * 16 + m;
      const float bb = biasl[c];
#pragma unroll
      for (int r = 0; r < 4; ++r) {
        const int grow = base + lr0 + r;
        if (grow < nrows) P[(size_t)grow * 64 + c] = f2bf(acc[nt][r] + bb);
      }
    }
  }
}

// ---------------- pass0: stats + scattered h1 store ----------------

__global__ __launch_bounds__(256) void edge_pass0(
    const float* __restrict__ ea, const int* __restrict__ rowidx,
    const int* __restrict__ inv, const float* __restrict__ W,
    const ushort* __restrict__ Pbf, ushort* __restrict__ h1s,
    float* __restrict__ ssum, float* __restrict__ ssq,
    int nrows, int ntiles) {
  __shared__ __align__(16) ushort Albs[64 * 72];
  __shared__ __align__(16) ushort Btl[64 * 72];
  __shared__ __align__(16) ushort Ol[64 * 72];   // h1 tile, f16
  __shared__ float wsum[4][64];
  __shared__ float wsq[4][64];
  __shared__ int inv_l[64];

  const int tid  = threadIdx.x;
  const int lane = tid & 63;
  const int wv   = tid >> 6;
  const int m    = lane & 15;
  const int quad = lane >> 4;

  for (int i = tid; i < 64 * 64; i += 256) {
    const int n = i >> 6, k = i & 63;
    Btl[n * 72 + k] = f2bf(W[(64 + k) * 64 + n]);   // bottom half of W1
  }
  wsum[wv][lane] = 0.f;
  wsq[wv][lane]  = 0.f;
  __syncthreads();
  short8 breg[2][4];
#pragma unroll
  for (int kc = 0; kc < 2; ++kc)
#pragma unroll
    for (int nt = 0; nt < 4; ++nt)
      breg[kc][nt] = *(const short8*)(&Btl[(nt * 16 + m) * 72 + kc * 32 + quad * 8]);

  for (int t = blockIdx.x; t < ntiles; t += gridDim.x) {
    __syncthreads();   // guards Albs / inv_l / Ol reuse across tiles
    const int base = t * 64;

    // P fragments for this wave's rows (issued early; latency hides under staging)
    float pv[4][4];
#pragma unroll
    for (int r = 0; r < 4; ++r) {
      const int grow = base + wv * 16 + quad * 4 + r;
      float p0 = 0.f, p1 = 0.f, p2 = 0.f, p3 = 0.f;
      if (grow < nrows) {
        const int prow = rowidx[grow];
        const ushort* pp = Pbf + (size_t)prow * 64 + m;
        p0 = bf2f(pp[0]);  p1 = bf2f(pp[16]);
        p2 = bf2f(pp[32]); p3 = bf2f(pp[48]);
      }
      pv[0][r] = p0; pv[1][r] = p1; pv[2][r] = p2; pv[3][r] = p3;
    }
    if (tid < 64) {
      const int grow = base + tid;
      inv_l[tid] = (grow < nrows) ? inv[grow] : 0;
    }
    for (int i = tid; i < 1024; i += 256) {
      const int e  = i >> 4;
      const int c4 = (i & 15) << 2;
      const int grow = base + e;
      f32x4 v = {0.f, 0.f, 0.f, 0.f};
      if (grow < nrows)
        v = __builtin_nontemporal_load((const f32x4*)(ea + (size_t)grow * 64 + c4));
      pack4(&Albs[e * 72 + c4], v);
    }
    __syncthreads();

    floatx4 acc[4];
#pragma unroll
    for (int nt = 0; nt < 4; ++nt) acc[nt] = (floatx4){0.f, 0.f, 0.f, 0.f};
    const ushort* arow = &Albs[(wv * 16 + m) * 72];
#pragma unroll
    for (int kc = 0; kc < 2; ++kc) {
      const short8 af = *(const short8*)(arow + kc * 32 + quad * 8);
#pragma unroll
      for (int nt = 0; nt < 4; ++nt)
        acc[nt] = __builtin_amdgcn_mfma_f32_16x16x32_bf16(af, breg[kc][nt], acc[nt], 0, 0, 0);
    }

    // epilogue: h1 -> Ol (f16) + column stats
    const int lr0 = wv * 16 + quad * 4;
#pragma unroll
    for (int nt = 0; nt < 4; ++nt) {
      const int c = nt * 16 + m;
      float s = 0.f, q = 0.f;
#pragma unroll
      for (int r = 0; r < 4; ++r) {
        const float h = acc[nt][r] + pv[nt][r];
        Ol[(lr0 + r) * 72 + c] = f2h(h);
        if (base + lr0 + r < nrows) { s += h; q += h * h; }
      }
      s += __shfl_xor(s, 16); s += __shfl_xor(s, 32);
      q += __shfl_xor(q, 16); q += __shfl_xor(q, 32);
      if (quad == 0) { wsum[wv][c] += s; wsq[wv][c] += q; }
    }
    __syncthreads();

    // scatter h1 rows (f16, 128B each) to sorted positions; posted stores, no stall
    for (int i = tid; i < 512; i += 256) {
      const int rrow = i >> 3;
      const int c8   = (i & 7) << 3;
      if (base + rrow < nrows) {
        const uint4 v = *(const uint4*)(&Ol[rrow * 72 + c8]);
        *(uint4*)(h1s + (size_t)inv_l[rrow] * 64 + c8) = v;
      }
    }
  }

  __syncthreads();
  if (tid < 128) {
    const int c = tid & 63;
    if (tid < 64) {
      unsafeAtomicAdd(&ssum[c], wsum[0][c] + wsum[1][c] + wsum[2][c] + wsum[3][c]);
    } else {
      unsafeAtomicAdd(&ssq[c], wsq[0][c] + wsq[1][c] + wsq[2][c] + wsq[3][c]);
    }
  }
}

// ---------------- streaming segmented mean (no atomics) ----------------

// walker = 8 lanes; each walker owns DC consecutive dests; rows are contiguous
// in h1s (sorted), so reads stream. Writes agg = mean directly (plain stores).
__global__ __launch_bounds__(256) void seg_reduce_dest(
    const ushort* __restrict__ h1s, const int* __restrict__ hist,
    const int* __restrict__ cursor_end, const float* __restrict__ scsh,
    float* __restrict__ agg, int N, int DC) {
  const int gid    = blockIdx.x * 256 + threadIdx.x;
  const int walker = gid >> 3;
  const int c0     = (gid & 7) << 3;
  const int d0     = walker * DC;
  if (d0 >= N) return;
  const int d1 = min(N, d0 + DC);

  float sc[8], sh[8];
#pragma unroll
  for (int j = 0; j < 8; ++j) {
    sc[j] = scsh[c0 + j];
    sh[j] = scsh[64 + c0 + j];
  }

  for (int d = d0; d < d1; ++d) {
    const int cnt = hist[d];
    const int en  = cursor_end[d];
    const int rs  = en - cnt;
    float a[8];
#pragma unroll
    for (int j = 0; j < 8; ++j) a[j] = 0.f;
    for (int r = rs; r < en; ++r) {
      const uint4 hv = *(const uint4*)(h1s + (size_t)r * 64 + c0);
      const ushort* hu = (const ushort*)&hv;
#pragma unroll
      for (int j = 0; j < 8; ++j)
        a[j] += silu(fmaf(h2f(hu[j]), sc[j], sh[j]));
    }
    const float inv = 1.0f / fmaxf((float)cnt, 1.0f);
    f32x4 o0 = {a[0] * inv, a[1] * inv, a[2] * inv, a[3] * inv};
    f32x4 o1 = {a[4] * inv, a[5] * inv, a[6] * inv, a[7] * inv};
    *(f32x4*)(agg + (size_t)d * 64 + c0)     = o0;
    *(f32x4*)(agg + (size_t)d * 64 + c0 + 4) = o1;
  }
}

// ---------------- sorted edge scatter (R2 fallback) ----------------

__global__ __launch_bounds__(256) void edge_pass1_sorted(
    const float* __restrict__ ea, const int* __restrict__ rowidx,
    const int* __restrict__ colidx, const int* __restrict__ perm,
    const float* __restrict__ W, const float* __restrict__ scsh,
    const ushort* __restrict__ Pbf, float* __restrict__ sums_out,
    int nrows, int ntiles) {
  __shared__ __align__(16) ushort Albs[64 * 72];
  __shared__ __align__(16) ushort Btl[64 * 72];
  __shared__ float Ol[64][66];
  __shared__ float scl[128];
  __shared__ int dest_l[64];

  const int tid  = threadIdx.x;
  const int lane = tid & 63;
  const int wv   = tid >> 6;
  const int m    = lane & 15;
  const int quad = lane >> 4;

  for (int i = tid; i < 64 * 64; i += 256) {
    const int n = i >> 6, k = i & 63;
    Btl[n * 72 + k] = f2bf(W[(64 + k) * 64 + n]);
  }
  if (tid < 128) scl[tid] = scsh[tid];
  __syncthreads();
  short8 breg[2][4];
#pragma unroll
  for (int kc = 0; kc < 2; ++kc)
#pragma unroll
    for (int nt = 0; nt < 4; ++nt)
      breg[kc][nt] = *(const short8*)(&Btl[(nt * 16 + m) * 72 + kc * 32 + quad * 8]);

  for (int t = blockIdx.x; t < ntiles; t += gridDim.x) {
    __syncthreads();
    const int base = t * 64;

    float pv[4][4];
#pragma unroll
    for (int r = 0; r < 4; ++r) {
      const int grow = base + wv * 16 + quad * 4 + r;
      float p0 = 0.f, p1 = 0.f, p2 = 0.f, p3 = 0.f;
      if (grow < nrows) {
        const int prow = rowidx[perm[grow]];
        const ushort* pp = Pbf + (size_t)prow * 64 + m;
        p0 = bf2f(pp[0]);  p1 = bf2f(pp[16]);
        p2 = bf2f(pp[32]); p3 = bf2f(pp[48]);
      }
      pv[0][r] = p0; pv[1][r] = p1; pv[2][r] = p2; pv[3][r] = p3;
    }
    if (tid < 64) {
      const int grow = base + tid;
      dest_l[tid] = (grow < nrows) ? colidx[perm[grow]] : -1;
    }
    for (int i = tid; i < 1024; i += 256) {
      const int e  = i >> 4;
      const int c4 = (i & 15) << 2;
      const int grow = base + e;
      f32x4 v = {0.f, 0.f, 0.f, 0.f};
      if (grow < nrows)
        v = __builtin_nontemporal_load((const f32x4*)(ea + (size_t)perm[grow] * 64 + c4));
      pack4(&Albs[e * 72 + c4], v);
    }
    __syncthreads();

    floatx4 acc[4];
#pragma unroll
    for (int nt = 0; nt < 4; ++nt) acc[nt] = (floatx4){0.f, 0.f, 0.f, 0.f};
    const ushort* arow = &Albs[(wv * 16 + m) * 72];
#pragma unroll
    for (int kc = 0; kc < 2; ++kc) {
      const short8 af = *(const short8*)(arow + kc * 32 + quad * 8);
#pragma unroll
      for (int nt = 0; nt < 4; ++nt)
        acc[nt] = __builtin_amdgcn_mfma_f32_16x16x32_bf16(af, breg[kc][nt], acc[nt], 0, 0, 0);
    }

    const int lr0 = wv * 16 + quad * 4;
#pragma unroll
    for (int nt = 0; nt < 4; ++nt) {
      const int c = nt * 16 + m;
      const float sc = scl[c];
      const float sh = scl[64 + c];
#pragma unroll
      for (int r = 0; r < 4; ++r) {
        const float h = acc[nt][r] + pv[nt][r];
        Ol[lr0 + r][c] = silu(h * sc + sh);
      }
    }
    __syncthreads();

    {
      const int c  = tid & 63;
      const int r0 = (tid >> 6) * 16;
      float a = 0.f;
      int cur = -1;
#pragma unroll
      for (int i = 0; i < 16; ++i) {
        const int d = dest_l[r0 + i];
        if (d != cur) {
          if (cur >= 0) unsafeAtomicAdd(&sums_out[(size_t)cur * 64 + c], a);
          cur = d;
          a = 0.f;
        }
        if (d >= 0) a += Ol[r0 + i][c];
      }
      if (cur >= 0) unsafeAtomicAdd(&sums_out[(size_t)cur * 64 + c], a);
    }
  }
}

// ---------------- fused GEMM (modes 0,2,3 + fallback mode 1) ----------------

// MODE: 0 = edge stats, 1 = edge scatter (fallback), 2 = node stats, 3 = node out
// USEP: 1 = K=64 GEMM + P-fragment accumulator init; 0 = legacy K=128 recompute
// cnt == nullptr (MODE 2/3): sums_in already holds the mean (agg).
template <int MODE, int USEP>
__global__ __launch_bounds__(256) void fused_gemm(
    const float* __restrict__ x, const float* __restrict__ ea,
    const float* __restrict__ sums_in, const float* __restrict__ cnt,
    const int* __restrict__ rowidx, const int* __restrict__ colidx,
    const float* __restrict__ W, const float* __restrict__ bias,
    const float* __restrict__ scsh, const ushort* __restrict__ Pbf,
    float* __restrict__ ssum, float* __restrict__ ssq,
    float* __restrict__ sums_out, float* __restrict__ cnt_out,
    float* __restrict__ out,
    float* __restrict__ zbuf, int zn,
    int nrows, int ntiles) {
  constexpr int KC = USEP ? 64 : 128;
  constexpr int KP = USEP ? 72 : 136;
  constexpr int CH = KC / 4;
  __shared__ __align__(16) ushort Albs[64 * KP];
  __shared__ __align__(16) ushort Btl[64 * KP];
  __shared__ float wsum[4][64];
  __shared__ float wsq[4][64];
  __shared__ float biasl[64];
  __shared__ float scl[128];
  __shared__ int coltile[64];

  const int tid  = threadIdx.x;
  const int lane = tid & 63;
  const int wv   = tid >> 6;
  const int m    = lane & 15;
  const int quad = lane >> 4;

  if (MODE == 0 && zbuf) {
    const int stride = gridDim.x * 256;
    const f32x4 z = {0.f, 0.f, 0.f, 0.f};
    for (int i = blockIdx.x * 256 + tid; i < (zn >> 2); i += stride)
      ((f32x4*)zbuf)[i] = z;
    if (blockIdx.x == 0 && tid < (zn & 3)) zbuf[(zn & ~3) + tid] = 0.f;
  }

  for (int i = tid; i < 64 * KC; i += 256) {
    const int n = i / KC, k = i % KC;
    const int gk = USEP ? (64 + k) : k;
    Btl[n * KP + k] = f2bf(W[gk * 64 + n]);
  }
  if (!USEP) { if (tid < 64) biasl[tid] = bias[tid]; }
  if (MODE == 1 || MODE == 3) {
    if (tid < 128) scl[tid] = scsh[tid];
  }
  if (MODE == 0 || MODE == 2) {
    wsum[wv][lane] = 0.f;
    wsq[wv][lane]  = 0.f;
  }
  __syncthreads();
  short8 breg[2][4];
  if constexpr (USEP) {
#pragma unroll
    for (int kc = 0; kc < 2; ++kc)
#pragma unroll
      for (int nt = 0; nt < 4; ++nt)
        breg[kc][nt] = *(const short8*)(&Btl[(nt * 16 + m) * KP + kc * 32 + quad * 8]);
  }

  for (int t = blockIdx.x; t < ntiles; t += gridDim.x) {
    __syncthreads();
    const int base = t * 64;

    float pv[4][4];
    if (USEP) {
#pragma unroll
      for (int r = 0; r < 4; ++r) {
        const int grow = base + wv * 16 + quad * 4 + r;
        float p0 = 0.f, p1 = 0.f, p2 = 0.f, p3 = 0.f;
        if (grow < nrows) {
          const int prow = (MODE <= 1) ? rowidx[grow] : grow;
          const ushort* pp = Pbf + (size_t)prow * 64 + m;
          p0 = bf2f(pp[0]);  p1 = bf2f(pp[16]);
          p2 = bf2f(pp[32]); p3 = bf2f(pp[48]);
        }
        pv[0][r] = p0; pv[1][r] = p1; pv[2][r] = p2; pv[3][r] = p3;
      }
    }

    for (int i = tid; i < 64 * CH; i += 256) {
      const int e  = i / CH;
      const int c4 = (i % CH) << 2;
      const int grow = base + e;
      f32x4 v = {0.f, 0.f, 0.f, 0.f};
      if (grow < nrows) {
        if (USEP) {
          if (MODE <= 1) {
            v = __builtin_nontemporal_load((const f32x4*)(ea + (size_t)grow * 64 + c4));
            if (MODE == 1 && c4 == 0) coltile[e] = colidx[grow];
          } else {
            v = *(const f32x4*)(sums_in + (size_t)grow * 64 + c4);
            if (cnt) {
              const float inv = 1.0f / fmaxf(cnt[grow], 1.0f);
              v *= inv;
            }
          }
        } else {
          if (MODE <= 1) {
            if (c4 < 64) {
              const int r = rowidx[grow];
              v = *(const f32x4*)(x + (size_t)r * 64 + c4);
            } else {
              v = __builtin_nontemporal_load((const f32x4*)(ea + (size_t)grow * 64 + (c4 - 64)));
            }
            if (MODE == 1 && c4 == 0) coltile[e] = colidx[grow];
          } else {
            if (c4 < 64) {
              v = *(const f32x4*)(x + (size_t)grow * 64 + c4);
            } else {
              v = *(const f32x4*)(sums_in + (size_t)grow * 64 + (c4 - 64));
              if (cnt) {
                const float inv = 1.0f / fmaxf(cnt[grow], 1.0f);
                v *= inv;
              }
            }
          }
        }
      }
      pack4(&Albs[e * KP + c4], v);
    }
    __syncthreads();

    floatx4 acc[4];
#pragma unroll
    for (int nt = 0; nt < 4; ++nt) acc[nt] = (floatx4){0.f, 0.f, 0.f, 0.f};
    const ushort* arow = &Albs[(wv * 16 + m) * KP];
#pragma unroll
    for (int kc = 0; kc < KC / 32; ++kc) {
      const short8 af = *(const short8*)(arow + kc * 32 + quad * 8);
#pragma unroll
      for (int nt = 0; nt < 4; ++nt) {
        short8 bfr;
        if constexpr (USEP) {
          bfr = breg[kc][nt];
        } else {
          bfr = *(const short8*)(&Btl[(nt * 16 + m) * KP + kc * 32 + quad * 8]);
        }
        acc[nt] = __builtin_amdgcn_mfma_f32_16x16x32_bf16(af, bfr, acc[nt], 0, 0, 0);
      }
    }

    const int lr0 = wv * 16 + quad * 4;
#pragma unroll
    for (int nt = 0; nt < 4; ++nt) {
      const int c = nt * 16 + m;
      const float bb = USEP ? 0.f : biasl[c];
      if (MODE == 0 || MODE == 2) {
        float s = 0.f, q = 0.f;
#pragma unroll
        for (int r = 0; r < 4; ++r) {
          const int grow = base + lr0 + r;
          if (grow < nrows) {
            const float v = acc[nt][r] + (USEP ? pv[nt][r] : bb);
            s += v;
            q += v * v;
          }
        }
        s += __shfl_xor(s, 16); s += __shfl_xor(s, 32);
        q += __shfl_xor(q, 16); q += __shfl_xor(q, 32);
        if (quad == 0) { wsum[wv][c] += s; wsq[wv][c] += q; }
      } else {
        const float sc = scl[c];
        const float sh = scl[64 + c];
#pragma unroll
        for (int r = 0; r < 4; ++r) {
          const int e = lr0 + r;
          const int grow = base + e;
          if (grow < nrows) {
            const float h = acc[nt][r] + (USEP ? pv[nt][r] : bb);
            const float o = silu(h * sc + sh);
            if (MODE == 1) {
              unsafeAtomicAdd(&sums_out[(size_t)coltile[e] * 64 + c], o);
            } else {
              __builtin_nontemporal_store(o, &out[(size_t)grow * 64 + c]);
            }
          }
        }
        if (MODE == 1 && nt == 0 && m == 0) {
#pragma unroll
          for (int r = 0; r < 4; ++r) {
            const int e = lr0 + r;
            if (base + e < nrows) unsafeAtomicAdd(&cnt_out[coltile[e]], 1.0f);
          }
        }
      }
    }
  }

  if (MODE == 0 || MODE == 2) {
    __syncthreads();
    if (tid < 128) {
      const int c = tid & 63;
      if (tid < 64) {
        unsafeAtomicAdd(&ssum[c], wsum[0][c] + wsum[1][c] + wsum[2][c] + wsum[3][c]);
      } else {
        unsafeAtomicAdd(&ssq[c], wsq[0][c] + wsq[1][c] + wsq[2][c] + wsq[3][c]);
      }
    }
  }
}

__global__ void finalize_stats(const float* __restrict__ ss, const float* __restrict__ sq,
                               const float* __restrict__ g, const float* __restrict__ be,
                               float* __restrict__ scsh, float invn) {
  const int c = threadIdx.x;  // 64 threads
  const float mu  = ss[c] * invn;
  const float var = sq[c] * invn - mu * mu;
  const float rs  = rsqrtf(fmaxf(var, 0.0f) + EPS);
  const float s   = g[c] * rs;
  scsh[c]      = s;
  scsh[64 + c] = be[c] - mu * s;
}

extern "C" void kernel_launch(void* const* d_in, const int* in_sizes, int n_in,
                              void* d_out, int out_size, void* d_ws, size_t ws_size,
                              hipStream_t stream) {
  const int N = in_sizes[0] / 64;
  const int E = in_sizes[1] / 64;
  const float* x   = (const float*)d_in[0];
  const float* ea  = (const float*)d_in[1];
  const float* W1  = (const float*)d_in[3];
  const float* b1  = (const float*)d_in[4];
  const float* g1  = (const float*)d_in[5];
  const float* be1 = (const float*)d_in[6];
  const float* W2  = (const float*)d_in[7];
  const float* b2  = (const float*)d_in[8];
  const float* g2  = (const float*)d_in[9];
  const float* be2 = (const float*)d_in[10];
  const int* ei   = (const int*)d_in[11];  // [2,E] int32
  const int* row  = ei;
  const int* colv = ei + E;

  const int ntE = (E + 63) / 64;
  const int ntN = (N + 63) / 64;
  const int gE  = ntE < 2048 ? ntE : 2048;
  const int gN  = ntN < 2048 ? ntN : 2048;
  const int nb  = (N + 2047) / 2048;

  // Top-path layout (words):
  //   sums/agg 64N | cntf N | statE 128 | statN 128 | scsh1 128 | scsh2 128 |
  //   hist N | curs N | bsum 2048 | inv E | Pbf 32N | h1s 32E (+align)
  const size_t needFull = (size_t)396 * N + (size_t)132 * E + 10256 + 64;
  const size_t needSort = ((size_t)N * 99 + (size_t)E + 2560 + 512) * sizeof(float);
  const size_t needP    = ((size_t)N * 97 + 512) * sizeof(float);

  if (ws_size >= needFull) {
    float* sums  = (float*)d_ws;            // also "agg" (mean) in top path
    float* cntf  = sums + (size_t)N * 64;
    float* statE = cntf + N;
    float* statN = statE + 128;
    float* scsh1 = statN + 128;
    float* scsh2 = scsh1 + 128;
    int*   hist  = (int*)(scsh2 + 128);
    int*   curs  = hist + N;
    int*   bsum  = curs + N;
    int*   inv   = bsum + 2048;
    ushort* Pbf  = (ushort*)(inv + E);
    ushort* h1s  = Pbf + (size_t)N * 64;
    h1s = (ushort*)(((uintptr_t)h1s + 15) & ~(uintptr_t)15);

    // statE..scsh2 (512 floats) + hist (N ints) are contiguous
    hipMemsetAsync(statE, 0, (512 + (size_t)N) * sizeof(float), stream);

    k_hist<<<dim3(1024), dim3(256), 0, stream>>>(colv, hist, E);
    k_scanA<<<dim3(nb), dim3(256), 0, stream>>>(hist, bsum, N);
    k_scanB<<<dim3(1), dim3(64), 0, stream>>>(bsum, nb);
    k_scanC<<<dim3(nb), dim3(256), 0, stream>>>(hist, bsum, curs, cntf, N);
    k_scatter<<<dim3(1024), dim3(256), 0, stream>>>(colv, curs, nullptr, inv, E);

    precompute_P<<<dim3(gN), dim3(256), 0, stream>>>(x, W1, b1, Pbf, N, ntN);
    edge_pass0<<<dim3(gE), dim3(256), 0, stream>>>(
        ea, row, inv, W1, Pbf, h1s, statE, statE + 64, E, ntE);
    finalize_stats<<<dim3(1), dim3(64), 0, stream>>>(statE, statE + 64, g1, be1, scsh1,
                                                     1.0f / (float)E);
    const int nwalk = (N + 3) / 4;
    const int segblocks = (nwalk * 8 + 255) / 256;
    seg_reduce_dest<<<dim3(segblocks), dim3(256), 0, stream>>>(
        h1s, hist, curs, scsh1, sums, N, 4);

    precompute_P<<<dim3(gN), dim3(256), 0, stream>>>(x, W2, b2, Pbf, N, ntN);
    fused_gemm<2, 1><<<dim3(gN), dim3(256), 0, stream>>>(
        x, nullptr, sums, nullptr, nullptr, nullptr, W2, b2, nullptr, Pbf,
        statN, statN + 64, nullptr, nullptr, nullptr, nullptr, 0, N, ntN);
    finalize_stats<<<dim3(1), dim3(64), 0, stream>>>(statN, statN + 64, g2, be2, scsh2,
                                                     1.0f / (float)N);
    fused_gemm<3, 1><<<dim3(gN), dim3(256), 0, stream>>>(
        x, nullptr, sums, nullptr, nullptr, nullptr, W2, b2, scsh2, Pbf,
        nullptr, nullptr, nullptr, nullptr, (float*)d_out, nullptr, 0, N, ntN);
    return;
  }

  if (ws_size >= needSort) {
    float* sums  = (float*)d_ws;
    float* cntf  = sums + (size_t)N * 64;
    float* statE = cntf + N;
    float* statN = statE + 128;
    float* scsh1 = statN + 128;
    float* scsh2 = scsh1 + 128;
    int*   hist  = (int*)(scsh2 + 128);
    int*   curs  = hist + N;
    int*   bsum  = curs + N;
    int*   perm  = bsum + 2048;
    ushort* Pbf  = (ushort*)(perm + E);

    hipMemsetAsync(statE, 0, (512 + (size_t)N) * sizeof(float), stream);

    k_hist<<<dim3(1024), dim3(256), 0, stream>>>(colv, hist, E);
    k_scanA<<<dim3(nb), dim3(256), 0, stream>>>(hist, bsum, N);
    k_scanB<<<dim3(1), dim3(64), 0, stream>>>(bsum, nb);
    k_scanC<<<dim3(nb), dim3(256), 0, stream>>>(hist, bsum, curs, cntf, N);
    k_scatter<<<dim3(1024), dim3(256), 0, stream>>>(colv, curs, perm, nullptr, E);

    precompute_P<<<dim3(gN), dim3(256), 0, stream>>>(x, W1, b1, Pbf, N, ntN);
    fused_gemm<0, 1><<<dim3(gE), dim3(256), 0, stream>>>(
        x, ea, nullptr, nullptr, row, nullptr, W1, b1, nullptr, Pbf,
        statE, statE + 64, nullptr, nullptr, nullptr, sums, N * 64, E, ntE);
    finalize_stats<<<dim3(1), dim3(64), 0, stream>>>(statE, statE + 64, g1, be1, scsh1,
                                                     1.0f / (float)E);
    edge_pass1_sorted<<<dim3(gE), dim3(256), 0, stream>>>(
        ea, row, colv, perm, W1, scsh1, Pbf, sums, E, ntE);
    precompute_P<<<dim3(gN), dim3(256), 0, stream>>>(x, W2, b2, Pbf, N, ntN);
    fused_gemm<2, 1><<<dim3(gN), dim3(256), 0, stream>>>(
        x, nullptr, sums, cntf, nullptr, nullptr, W2, b2, nullptr, Pbf,
        statN, statN + 64, nullptr, nullptr, nullptr, nullptr, 0, N, ntN);
    finalize_stats<<<dim3(1), dim3(64), 0, stream>>>(statN, statN + 64, g2, be2, scsh2,
                                                     1.0f / (float)N);
    fused_gemm<3, 1><<<dim3(gN), dim3(256), 0, stream>>>(
        x, nullptr, sums, cntf, nullptr, nullptr, W2, b2, scsh2, Pbf,
        nullptr, nullptr, nullptr, nullptr, (float*)d_out, nullptr, 0, N, ntN);
    return;
  }

  // -------- legacy fallbacks --------
  float* sums  = (float*)d_ws;
  float* cnt   = sums + (size_t)N * 64;
  float* statE = cnt + N;
  float* statN = statE + 128;
  float* scsh1 = statN + 128;
  float* scsh2 = scsh1 + 128;
  ushort* Pbf  = (ushort*)(scsh2 + 128);
  const bool useP = (ws_size >= needP);
  const int zn = N * 65;

  hipMemsetAsync(statE, 0, 512 * sizeof(float), stream);

  if (useP) {
    precompute_P<<<dim3(gN), dim3(256), 0, stream>>>(x, W1, b1, Pbf, N, ntN);
    fused_gemm<0, 1><<<dim3(gE), dim3(256), 0, stream>>>(
        x, ea, nullptr, nullptr, row, nullptr, W1, b1, nullptr, Pbf,
        statE, statE + 64, nullptr, nullptr, nullptr, sums, zn, E, ntE);
    finalize_stats<<<dim3(1), dim3(64), 0, stream>>>(statE, statE + 64, g1, be1, scsh1,
                                                     1.0f / (float)E);
    fused_gemm<1, 1><<<dim3(gE), dim3(256), 0, stream>>>(
        x, ea, nullptr, nullptr, row, colv, W1, b1, scsh1, Pbf,
        nullptr, nullptr, sums, cnt, nullptr, nullptr, 0, E, ntE);
    precompute_P<<<dim3(gN), dim3(256), 0, stream>>>(x, W2, b2, Pbf, N, ntN);
    fused_gemm<2, 1><<<dim3(gN), dim3(256), 0, stream>>>(
        x, nullptr, sums, cnt, nullptr, nullptr, W2, b2, nullptr, Pbf,
        statN, statN + 64, nullptr, nullptr, nullptr, nullptr, 0, N, ntN);
    finalize_stats<<<dim3(1), dim3(64), 0, stream>>>(statN, statN + 64, g2, be2, scsh2,
                                                     1.0f / (float)N);
    fused_gemm<3, 1><<<dim3(gN), dim3(256), 0, stream>>>(
        x, nullptr, sums, cnt, nullptr, nullptr, W2, b2, scsh2, Pbf,
        nullptr, nullptr, nullptr, nullptr, (float*)d_out, nullptr, 0, N, ntN);
  } else {
    fused_gemm<0, 0><<<dim3(gE), dim3(256), 0, stream>>>(
        x, ea, nullptr, nullptr, row, nullptr, W1, b1, nullptr, nullptr,
        statE, statE + 64, nullptr, nullptr, nullptr, sums, zn, E, ntE);
    finalize_stats<<<dim3(1), dim3(64), 0, stream>>>(statE, statE + 64, g1, be1, scsh1,
                                                     1.0f / (float)E);
    fused_gemm<1, 0><<<dim3(gE), dim3(256), 0, stream>>>(
        x, ea, nullptr, nullptr, row, colv, W1, b1, scsh1, nullptr,
        nullptr, nullptr, sums, cnt, nullptr, nullptr, 0, E, ntE);
    fused_gemm<2, 0><<<dim3(gN), dim3(256), 0, stream>>>(
        x, nullptr, sums, cnt, nullptr, nullptr, W2, b2, nullptr, nullptr,
        statN, statN + 64, nullptr, nullptr, nullptr, nullptr, 0, N, ntN);
    finalize_stats<<<dim3(1), dim3(64), 0, stream>>>(statN, statN + 64, g2, be2, scsh2,
                                                     1.0f / (float)N);
    fused_gemm<3, 0><<<dim3(gN), dim3(256), 0, stream>>>(
        x, nullptr, sums, cnt, nullptr, nullptr, W2, b2, scsh2, nullptr,
        nullptr, nullptr, nullptr, nullptr, (float*)d_out, nullptr, 0, N, ntN);
  }
}

// Round 4
// 699.954 us; speedup vs baseline: 1.2881x; 1.0770x over previous
//
#include <hip/hip_runtime.h>
#include <hip/hip_fp16.h>
#include <stdint.h>

// NodeModel: edge MLP (Lin 128->64 + BN(batch stats) + SiLU) -> scatter_mean -> node MLP.
// v4: barrier-free edge pass + fused launch chain.
//   P1/P2 = x @ W{1,2}_top + b (bf16) -- one kernel, x read once (if ws fits)
//   hist -> scan (2 kernels) -> curs
//   pass0: ea GEMM (A-frags direct global->reg, no tile barriers) + P1[row]
//          -> stats + h1(f16) scattered to h1s[atomic slot]  (k_scatter folded in)
//   seg_reduce: stream h1s sorted, norm+SiLU (scsh computed in-block), mean -> agg
//   g2: [P2 | agg] GEMM -> stats ; g3: same + inline finalize -> out
// Fallbacks: R3 paths preserved (sorted-gather -> P -> legacy).

#define EPS 1e-5f

using short8  = __attribute__((ext_vector_type(8))) short;
using floatx4 = __attribute__((ext_vector_type(4))) float;
using f32x4   = __attribute__((ext_vector_type(4))) float;

__device__ __forceinline__ ushort f2bf(float f) {
  uint32_t u = __builtin_bit_cast(uint32_t, f);
  u += 0x7fffu + ((u >> 16) & 1u);   // RNE
  return (ushort)(u >> 16);
}
__device__ __forceinline__ float bf2f(ushort u) {
  uint32_t x = ((uint32_t)u) << 16;
  return __builtin_bit_cast(float, x);
}
__device__ __forceinline__ ushort f2h(float f) {
  __half h = __float2half(f);   // RNE
  return *reinterpret_cast<ushort*>(&h);
}
__device__ __forceinline__ float h2f(ushort u) {
  __half h;
  *reinterpret_cast<ushort*>(&h) = u;
  return __half2float(h);
}
__device__ __forceinline__ float silu(float v) {
  return v / (1.0f + __expf(-v));
}
__device__ __forceinline__ void pack4(ushort* dst, f32x4 v) {
  uint2 p;
  p.x = (uint)f2bf(v.x) | ((uint)f2bf(v.y) << 16);
  p.y = (uint)f2bf(v.z) | ((uint)f2bf(v.w) << 16);
  *(uint2*)dst = p;
}
__device__ __forceinline__ short8 cvt8(f32x4 a, f32x4 b) {
  short8 r;
  r[0] = (short)f2bf(a.x); r[1] = (short)f2bf(a.y);
  r[2] = (short)f2bf(a.z); r[3] = (short)f2bf(a.w);
  r[4] = (short)f2bf(b.x); r[5] = (short)f2bf(b.y);
  r[6] = (short)f2bf(b.z); r[7] = (short)f2bf(b.w);
  return r;
}

// ---------------- sort machinery ----------------

__global__ __launch_bounds__(256) void k_hist(const int* __restrict__ col,
                                              int* __restrict__ hist, int E) {
  const int stride = gridDim.x * 256;
  for (int e = blockIdx.x * 256 + threadIdx.x; e < E; e += stride)
    atomicAdd(&hist[col[e]], 1);
}

__global__ __launch_bounds__(256) void k_scanA(const int* __restrict__ hist,
                                               int* __restrict__ bsum, int n) {
  __shared__ int sd[256];
  const int tid = threadIdx.x;
  const int base = blockIdx.x * 2048 + tid * 8;
  int s = 0;
#pragma unroll
  for (int j = 0; j < 8; ++j) {
    const int i = base + j;
    if (i < n) s += hist[i];
  }
  sd[tid] = s;
  __syncthreads();
  for (int off = 128; off > 0; off >>= 1) {
    if (tid < off) sd[tid] += sd[tid + off];
    __syncthreads();
  }
  if (tid == 0) bsum[blockIdx.x] = sd[0];
}

// scanB folded in: each block computes its own prefix of bsum (nb <= ~64 entries).
__global__ __launch_bounds__(256) void k_scanC2(const int* __restrict__ hist,
                                                const int* __restrict__ bsum, int nb,
                                                int* __restrict__ cursor,
                                                float* __restrict__ cntf, int n) {
  __shared__ int sd[256];
  __shared__ int boff;
  const int tid = threadIdx.x;
  if (tid < 64) {
    int acc = 0;
    for (int j = tid; j < blockIdx.x; j += 64) acc += bsum[j];
#pragma unroll
    for (int off = 1; off < 64; off <<= 1) acc += __shfl_xor(acc, off);
    if (tid == 0) boff = acc;
  }
  const int base = blockIdx.x * 2048 + tid * 8;
  int loc[8];
  int s = 0;
#pragma unroll
  for (int j = 0; j < 8; ++j) {
    const int i = base + j;
    loc[j] = s;
    if (i < n) s += hist[i];
  }
  const int own = s;
  sd[tid] = s;
  __syncthreads();
  for (int off = 1; off < 256; off <<= 1) {
    const int v = (tid >= off) ? sd[tid - off] : 0;
    __syncthreads();
    sd[tid] += v;
    __syncthreads();
  }
  const int add = boff + sd[tid] - own;
#pragma unroll
  for (int j = 0; j < 8; ++j) {
    const int i = base + j;
    if (i < n) {
      cursor[i] = add + loc[j];
      if (cntf) cntf[i] = (float)hist[i];
    }
  }
}

// fallback (sorted-gather path) only
__global__ __launch_bounds__(256) void k_scatter(const int* __restrict__ col,
                                                 int* __restrict__ cursor,
                                                 int* __restrict__ perm, int E) {
  const int stride = gridDim.x * 256;
  for (int e = blockIdx.x * 256 + threadIdx.x; e < E; e += stride) {
    const int d = col[e];
    const int pos = atomicAdd(&cursor[d], 1);
    perm[pos] = e;
  }
}

// ---------------- P precompute (one or two weight sets, x read once) ----------------

// P_i = x @ Wi_top + bi, stored bf16 [N,64]. Barrier-free tile loop:
// A-frags loaded global->reg; output transposed via per-wave LDS slice.
__global__ __launch_bounds__(256) void precompute_P12(
    const float* __restrict__ x,
    const float* __restrict__ W1, const float* __restrict__ b1,
    const float* __restrict__ W2, const float* __restrict__ b2,
    ushort* __restrict__ P1, ushort* __restrict__ P2,
    int nrows, int ntiles) {
  __shared__ __align__(16) ushort SB[64 * 72];   // W^T stage -> per-wave Ol slices
  __shared__ float bias1l[64];
  __shared__ float bias2l[64];

  const int tid  = threadIdx.x;
  const int lane = tid & 63;
  const int wv   = tid >> 6;
  const int m    = lane & 15;
  const int quad = lane >> 4;
  const bool twoW = (P2 != nullptr);

  for (int i = tid; i < 64 * 64; i += 256) {
    const int n = i >> 6, k = i & 63;
    SB[n * 72 + k] = f2bf(W1[k * 64 + n]);
  }
  if (tid < 64) bias1l[tid] = b1[tid];
  __syncthreads();
  short8 breg1[2][4], breg2[2][4];
#pragma unroll
  for (int kc = 0; kc < 2; ++kc)
#pragma unroll
    for (int nt = 0; nt < 4; ++nt)
      breg1[kc][nt] = *(const short8*)(&SB[(nt * 16 + m) * 72 + kc * 32 + quad * 8]);
  __syncthreads();
  if (twoW) {
    for (int i = tid; i < 64 * 64; i += 256) {
      const int n = i >> 6, k = i & 63;
      SB[n * 72 + k] = f2bf(W2[k * 64 + n]);
    }
    if (tid < 64) bias2l[tid] = b2[tid];
    __syncthreads();
#pragma unroll
    for (int kc = 0; kc < 2; ++kc)
#pragma unroll
      for (int nt = 0; nt < 4; ++nt)
        breg2[kc][nt] = *(const short8*)(&SB[(nt * 16 + m) * 72 + kc * 32 + quad * 8]);
    __syncthreads();
  }

  ushort* ol = &SB[wv * 1152];   // 16 rows x 72

  for (int t = blockIdx.x; t < ntiles; t += gridDim.x) {
    const int g0 = t * 64 + wv * 16;
    const int arow = g0 + m;
    const bool av = arow < nrows;
    short8 af[2];
#pragma unroll
    for (int kc = 0; kc < 2; ++kc) {
      f32x4 a0 = {0.f, 0.f, 0.f, 0.f}, a1 = {0.f, 0.f, 0.f, 0.f};
      if (av) {
        const float* p = x + (size_t)arow * 64 + kc * 32 + quad * 8;
        a0 = *(const f32x4*)p;
        a1 = *(const f32x4*)(p + 4);
      }
      af[kc] = cvt8(a0, a1);
    }
    floatx4 acc1[4], acc2[4];
#pragma unroll
    for (int nt = 0; nt < 4; ++nt) {
      acc1[nt] = (floatx4){0.f, 0.f, 0.f, 0.f};
      acc2[nt] = (floatx4){0.f, 0.f, 0.f, 0.f};
    }
#pragma unroll
    for (int kc = 0; kc < 2; ++kc)
#pragma unroll
      for (int nt = 0; nt < 4; ++nt) {
        acc1[nt] = __builtin_amdgcn_mfma_f32_16x16x32_bf16(af[kc], breg1[kc][nt], acc1[nt], 0, 0, 0);
        if (twoW)
          acc2[nt] = __builtin_amdgcn_mfma_f32_16x16x32_bf16(af[kc], breg2[kc][nt], acc2[nt], 0, 0, 0);
      }
    const int lr0 = quad * 4;
    // P1: transpose via per-wave slice then 16B row stores
#pragma unroll
    for (int nt = 0; nt < 4; ++nt) {
      const int c = nt * 16 + m;
      const float bb = bias1l[c];
#pragma unroll
      for (int r = 0; r < 4; ++r) ol[(lr0 + r) * 72 + c] = f2bf(acc1[nt][r] + bb);
    }
#pragma unroll
    for (int j = 0; j < 2; ++j) {
      const int lr = j * 8 + (lane >> 3);
      const int grow = g0 + lr;
      if (grow < nrows) {
        const int c8 = (lane & 7) * 8;
        const uint4 v = *(const uint4*)(ol + lr * 72 + c8);
        *(uint4*)(P1 + (size_t)grow * 64 + c8) = v;
      }
    }
    if (twoW) {
#pragma unroll
      for (int nt = 0; nt < 4; ++nt) {
        const int c = nt * 16 + m;
        const float bb = bias2l[c];
#pragma unroll
        for (int r = 0; r < 4; ++r) ol[(lr0 + r) * 72 + c] = f2bf(acc2[nt][r] + bb);
      }
#pragma unroll
      for (int j = 0; j < 2; ++j) {
        const int lr = j * 8 + (lane >> 3);
        const int grow = g0 + lr;
        if (grow < nrows) {
          const int c8 = (lane & 7) * 8;
          const uint4 v = *(const uint4*)(ol + lr * 72 + c8);
          *(uint4*)(P2 + (size_t)grow * 64 + c8) = v;
        }
      }
    }
  }
}

// ---------------- pass0 v2: barrier-free GEMM + stats + inline-slot scatter ----------------

__global__ __launch_bounds__(256) void edge_pass0_v2(
    const float* __restrict__ ea, const int* __restrict__ rowidx,
    const int* __restrict__ colidx, int* __restrict__ curs,
    const float* __restrict__ W, const ushort* __restrict__ Pbf,
    ushort* __restrict__ h1s, float* __restrict__ ssum, float* __restrict__ ssq,
    int nrows, int ntiles) {
  __shared__ __align__(16) ushort SB[64 * 72];   // W^T stage -> per-wave Ol slices
  __shared__ float wsum[4][64];
  __shared__ float wsq[4][64];

  const int tid  = threadIdx.x;
  const int lane = tid & 63;
  const int wv   = tid >> 6;
  const int m    = lane & 15;
  const int quad = lane >> 4;

  for (int i = tid; i < 64 * 64; i += 256) {
    const int n = i >> 6, k = i & 63;
    SB[n * 72 + k] = f2bf(W[(64 + k) * 64 + n]);   // bottom half of W1
  }
  wsum[wv][lane] = 0.f;
  wsq[wv][lane]  = 0.f;
  __syncthreads();
  short8 breg[2][4];
#pragma unroll
  for (int kc = 0; kc < 2; ++kc)
#pragma unroll
    for (int nt = 0; nt < 4; ++nt)
      breg[kc][nt] = *(const short8*)(&SB[(nt * 16 + m) * 72 + kc * 32 + quad * 8]);
  __syncthreads();   // SB now reusable as per-wave Ol

  ushort* ol = &SB[wv * 1152];

  for (int t = blockIdx.x; t < ntiles; t += gridDim.x) {
    const int g0 = t * 64 + wv * 16;
    // A-fragments: direct global->reg (contiguous 32B per lane per kc)
    const int arow = g0 + m;
    const bool av = arow < nrows;
    short8 af[2];
#pragma unroll
    for (int kc = 0; kc < 2; ++kc) {
      f32x4 a0 = {0.f, 0.f, 0.f, 0.f}, a1 = {0.f, 0.f, 0.f, 0.f};
      if (av) {
        const float* p = ea + (size_t)arow * 64 + kc * 32 + quad * 8;
        a0 = *(const f32x4*)p;
        a1 = *(const f32x4*)(p + 4);
      }
      af[kc] = cvt8(a0, a1);
    }
    // P fragments for this wave's rows
    float pv[4][4];
#pragma unroll
    for (int r = 0; r < 4; ++r) {
      const int grow = g0 + quad * 4 + r;
      float p0 = 0.f, p1 = 0.f, p2 = 0.f, p3 = 0.f;
      if (grow < nrows) {
        const int prow = rowidx[grow];
        const ushort* pp = Pbf + (size_t)prow * 64 + m;
        p0 = bf2f(pp[0]);  p1 = bf2f(pp[16]);
        p2 = bf2f(pp[32]); p3 = bf2f(pp[48]);
      }
      pv[0][r] = p0; pv[1][r] = p1; pv[2][r] = p2; pv[3][r] = p3;
    }
    // destination slot (sorted position) via inline atomic; lanes 0..15 own rows
    int pos = 0;
    if (lane < 16) {
      const int grow = g0 + lane;
      if (grow < nrows) pos = atomicAdd(&curs[colidx[grow]], 1);
    }
    // MFMA
    floatx4 acc[4];
#pragma unroll
    for (int nt = 0; nt < 4; ++nt) acc[nt] = (floatx4){0.f, 0.f, 0.f, 0.f};
#pragma unroll
    for (int kc = 0; kc < 2; ++kc)
#pragma unroll
      for (int nt = 0; nt < 4; ++nt)
        acc[nt] = __builtin_amdgcn_mfma_f32_16x16x32_bf16(af[kc], breg[kc][nt], acc[nt], 0, 0, 0);
    // stats + f16 tile into per-wave Ol slice (wave-private: no barrier)
    const int lr0 = quad * 4;
#pragma unroll
    for (int nt = 0; nt < 4; ++nt) {
      const int c = nt * 16 + m;
      float s = 0.f, q = 0.f;
#pragma unroll
      for (int r = 0; r < 4; ++r) {
        const float h = acc[nt][r] + pv[nt][r];
        ol[(lr0 + r) * 72 + c] = f2h(h);
        if (g0 + lr0 + r < nrows) { s += h; q += h * h; }
      }
      s += __shfl_xor(s, 16); s += __shfl_xor(s, 32);
      q += __shfl_xor(q, 16); q += __shfl_xor(q, 32);
      if (quad == 0) { wsum[wv][c] += s; wsq[wv][c] += q; }
    }
    // scatter rows (128B f16 each) to their sorted slots; posted stores
#pragma unroll
    for (int j = 0; j < 2; ++j) {
      const int lr = j * 8 + (lane >> 3);
      const int grow = g0 + lr;
      const int p = __shfl(pos, lr);
      if (grow < nrows) {
        const int c8 = (lane & 7) * 8;
        const uint4 v = *(const uint4*)(ol + lr * 72 + c8);
        *(uint4*)(h1s + (size_t)p * 64 + c8) = v;
      }
    }
  }

  __syncthreads();
  if (tid < 128) {
    const int c = tid & 63;
    if (tid < 64) {
      unsafeAtomicAdd(&ssum[c], wsum[0][c] + wsum[1][c] + wsum[2][c] + wsum[3][c]);
    } else {
      unsafeAtomicAdd(&ssq[c], wsq[0][c] + wsq[1][c] + wsq[2][c] + wsq[3][c]);
    }
  }
}

// ---------------- streaming segmented mean (scsh computed in-block) ----------------

__global__ __launch_bounds__(256) void seg_reduce_v2(
    const ushort* __restrict__ h1s, const int* __restrict__ hist,
    const int* __restrict__ curs_end, const float* __restrict__ statE,
    const float* __restrict__ gam, const float* __restrict__ bet,
    float* __restrict__ agg, int N, float invE) {
  __shared__ float scl[128];
  const int tid = threadIdx.x;
  if (tid < 64) {
    const float mu  = statE[tid] * invE;
    const float var = statE[64 + tid] * invE - mu * mu;
    const float rs  = rsqrtf(fmaxf(var, 0.0f) + EPS);
    const float s   = gam[tid] * rs;
    scl[tid]      = s;
    scl[64 + tid] = bet[tid] - mu * s;
  }
  __syncthreads();

  const int gid    = blockIdx.x * 256 + tid;
  const int walker = gid >> 3;
  const int c0     = (gid & 7) << 3;
  const int d0     = walker * 2;
  if (d0 >= N) return;
  const int d1 = min(N, d0 + 2);

  float sc[8], sh[8];
#pragma unroll
  for (int j = 0; j < 8; ++j) {
    sc[j] = scl[c0 + j];
    sh[j] = scl[64 + c0 + j];
  }
  for (int d = d0; d < d1; ++d) {
    const int cnt = hist[d];
    const int en  = curs_end[d];
    const int rs  = en - cnt;
    float a[8];
#pragma unroll
    for (int j = 0; j < 8; ++j) a[j] = 0.f;
    for (int r = rs; r < en; ++r) {
      const uint4 hv = *(const uint4*)(h1s + (size_t)r * 64 + c0);
      const ushort* hu = (const ushort*)&hv;
#pragma unroll
      for (int j = 0; j < 8; ++j)
        a[j] += silu(fmaf(h2f(hu[j]), sc[j], sh[j]));
    }
    const float inv = 1.0f / fmaxf((float)cnt, 1.0f);
    f32x4 o0 = {a[0] * inv, a[1] * inv, a[2] * inv, a[3] * inv};
    f32x4 o1 = {a[4] * inv, a[5] * inv, a[6] * inv, a[7] * inv};
    *(f32x4*)(agg + (size_t)d * 64 + c0)     = o0;
    *(f32x4*)(agg + (size_t)d * 64 + c0 + 4) = o1;
  }
}

// ---------------- sorted edge scatter (R2/R3 fallback) ----------------

__global__ __launch_bounds__(256) void edge_pass1_sorted(
    const float* __restrict__ ea, const int* __restrict__ rowidx,
    const int* __restrict__ colidx, const int* __restrict__ perm,
    const float* __restrict__ W, const float* __restrict__ scsh,
    const ushort* __restrict__ Pbf, float* __restrict__ sums_out,
    int nrows, int ntiles) {
  __shared__ __align__(16) ushort Albs[64 * 72];
  __shared__ __align__(16) ushort Btl[64 * 72];
  __shared__ float Ol[64][66];
  __shared__ float scl[128];
  __shared__ int dest_l[64];

  const int tid  = threadIdx.x;
  const int lane = tid & 63;
  const int wv   = tid >> 6;
  const int m    = lane & 15;
  const int quad = lane >> 4;

  for (int i = tid; i < 64 * 64; i += 256) {
    const int n = i >> 6, k = i & 63;
    Btl[n * 72 + k] = f2bf(W[(64 + k) * 64 + n]);
  }
  if (tid < 128) scl[tid] = scsh[tid];
  __syncthreads();
  short8 breg[2][4];
#pragma unroll
  for (int kc = 0; kc < 2; ++kc)
#pragma unroll
    for (int nt = 0; nt < 4; ++nt)
      breg[kc][nt] = *(const short8*)(&Btl[(nt * 16 + m) * 72 + kc * 32 + quad * 8]);

  for (int t = blockIdx.x; t < ntiles; t += gridDim.x) {
    __syncthreads();
    const int base = t * 64;

    float pv[4][4];
#pragma unroll
    for (int r = 0; r < 4; ++r) {
      const int grow = base + wv * 16 + quad * 4 + r;
      float p0 = 0.f, p1 = 0.f, p2 = 0.f, p3 = 0.f;
      if (grow < nrows) {
        const int prow = rowidx[perm[grow]];
        const ushort* pp = Pbf + (size_t)prow * 64 + m;
        p0 = bf2f(pp[0]);  p1 = bf2f(pp[16]);
        p2 = bf2f(pp[32]); p3 = bf2f(pp[48]);
      }
      pv[0][r] = p0; pv[1][r] = p1; pv[2][r] = p2; pv[3][r] = p3;
    }
    if (tid < 64) {
      const int grow = base + tid;
      dest_l[tid] = (grow < nrows) ? colidx[perm[grow]] : -1;
    }
    for (int i = tid; i < 1024; i += 256) {
      const int e  = i >> 4;
      const int c4 = (i & 15) << 2;
      const int grow = base + e;
      f32x4 v = {0.f, 0.f, 0.f, 0.f};
      if (grow < nrows)
        v = __builtin_nontemporal_load((const f32x4*)(ea + (size_t)perm[grow] * 64 + c4));
      pack4(&Albs[e * 72 + c4], v);
    }
    __syncthreads();

    floatx4 acc[4];
#pragma unroll
    for (int nt = 0; nt < 4; ++nt) acc[nt] = (floatx4){0.f, 0.f, 0.f, 0.f};
    const ushort* arow = &Albs[(wv * 16 + m) * 72];
#pragma unroll
    for (int kc = 0; kc < 2; ++kc) {
      const short8 af = *(const short8*)(arow + kc * 32 + quad * 8);
#pragma unroll
      for (int nt = 0; nt < 4; ++nt)
        acc[nt] = __builtin_amdgcn_mfma_f32_16x16x32_bf16(af, breg[kc][nt], acc[nt], 0, 0, 0);
    }

    const int lr0 = wv * 16 + quad * 4;
#pragma unroll
    for (int nt = 0; nt < 4; ++nt) {
      const int c = nt * 16 + m;
      const float sc = scl[c];
      const float sh = scl[64 + c];
#pragma unroll
      for (int r = 0; r < 4; ++r) {
        const float h = acc[nt][r] + pv[nt][r];
        Ol[lr0 + r][c] = silu(h * sc + sh);
      }
    }
    __syncthreads();

    {
      const int c  = tid & 63;
      const int r0 = (tid >> 6) * 16;
      float a = 0.f;
      int cur = -1;
#pragma unroll
      for (int i = 0; i < 16; ++i) {
        const int d = dest_l[r0 + i];
        if (d != cur) {
          if (cur >= 0) unsafeAtomicAdd(&sums_out[(size_t)cur * 64 + c], a);
          cur = d;
          a = 0.f;
        }
        if (d >= 0) a += Ol[r0 + i][c];
      }
      if (cur >= 0) unsafeAtomicAdd(&sums_out[(size_t)cur * 64 + c], a);
    }
  }
}

// ---------------- fused GEMM (modes 0,2,3 + fallback mode 1) ----------------

// MODE: 0 = edge stats, 1 = edge scatter (fallback), 2 = node stats, 3 = node out
// USEP: 1 = K=64 GEMM + P-fragment accumulator init; 0 = legacy K=128 recompute
// cnt == nullptr (MODE 2/3): sums_in already holds the mean (agg).
// MODE==3 && finS != nullptr: compute scale/shift in-block from finS stats (fused finalize).
template <int MODE, int USEP>
__global__ __launch_bounds__(256) void fused_gemm(
    const float* __restrict__ x, const float* __restrict__ ea,
    const float* __restrict__ sums_in, const float* __restrict__ cnt,
    const int* __restrict__ rowidx, const int* __restrict__ colidx,
    const float* __restrict__ W, const float* __restrict__ bias,
    const float* __restrict__ scsh, const ushort* __restrict__ Pbf,
    float* __restrict__ ssum, float* __restrict__ ssq,
    float* __restrict__ sums_out, float* __restrict__ cnt_out,
    float* __restrict__ out,
    float* __restrict__ zbuf, int zn,
    const float* __restrict__ finS, const float* __restrict__ fing,
    const float* __restrict__ finb, float invn,
    int nrows, int ntiles) {
  constexpr int KC = USEP ? 64 : 128;
  constexpr int KP = USEP ? 72 : 136;
  constexpr int CH = KC / 4;
  __shared__ __align__(16) ushort Albs[64 * KP];
  __shared__ __align__(16) ushort Btl[64 * KP];
  __shared__ float wsum[4][64];
  __shared__ float wsq[4][64];
  __shared__ float biasl[64];
  __shared__ float scl[128];
  __shared__ int coltile[64];

  const int tid  = threadIdx.x;
  const int lane = tid & 63;
  const int wv   = tid >> 6;
  const int m    = lane & 15;
  const int quad = lane >> 4;

  if (MODE == 0 && zbuf) {
    const int stride = gridDim.x * 256;
    const f32x4 z = {0.f, 0.f, 0.f, 0.f};
    for (int i = blockIdx.x * 256 + tid; i < (zn >> 2); i += stride)
      ((f32x4*)zbuf)[i] = z;
    if (blockIdx.x == 0 && tid < (zn & 3)) zbuf[(zn & ~3) + tid] = 0.f;
  }

  for (int i = tid; i < 64 * KC; i += 256) {
    const int n = i / KC, k = i % KC;
    const int gk = USEP ? (64 + k) : k;
    Btl[n * KP + k] = f2bf(W[gk * 64 + n]);
  }
  if (!USEP) { if (tid < 64) biasl[tid] = bias[tid]; }
  if (MODE == 3) {
    if (finS) {
      if (tid < 64) {
        const float mu  = finS[tid] * invn;
        const float var = finS[64 + tid] * invn - mu * mu;
        const float rs  = rsqrtf(fmaxf(var, 0.0f) + EPS);
        const float s   = fing[tid] * rs;
        scl[tid]      = s;
        scl[64 + tid] = finb[tid] - mu * s;
      }
    } else if (tid < 128) scl[tid] = scsh[tid];
  }
  if (MODE == 1) {
    if (tid < 128) scl[tid] = scsh[tid];
  }
  if (MODE == 0 || MODE == 2) {
    wsum[wv][lane] = 0.f;
    wsq[wv][lane]  = 0.f;
  }
  __syncthreads();
  short8 breg[2][4];
  if constexpr (USEP) {
#pragma unroll
    for (int kc = 0; kc < 2; ++kc)
#pragma unroll
      for (int nt = 0; nt < 4; ++nt)
        breg[kc][nt] = *(const short8*)(&Btl[(nt * 16 + m) * KP + kc * 32 + quad * 8]);
  }

  for (int t = blockIdx.x; t < ntiles; t += gridDim.x) {
    __syncthreads();
    const int base = t * 64;

    float pv[4][4];
    if (USEP) {
#pragma unroll
      for (int r = 0; r < 4; ++r) {
        const int grow = base + wv * 16 + quad * 4 + r;
        float p0 = 0.f, p1 = 0.f, p2 = 0.f, p3 = 0.f;
        if (grow < nrows) {
          const int prow = (MODE <= 1) ? rowidx[grow] : grow;
          const ushort* pp = Pbf + (size_t)prow * 64 + m;
          p0 = bf2f(pp[0]);  p1 = bf2f(pp[16]);
          p2 = bf2f(pp[32]); p3 = bf2f(pp[48]);
        }
        pv[0][r] = p0; pv[1][r] = p1; pv[2][r] = p2; pv[3][r] = p3;
      }
    }

    for (int i = tid; i < 64 * CH; i += 256) {
      const int e  = i / CH;
      const int c4 = (i % CH) << 2;
      const int grow = base + e;
      f32x4 v = {0.f, 0.f, 0.f, 0.f};
      if (grow < nrows) {
        if (USEP) {
          if (MODE <= 1) {
            v = __builtin_nontemporal_load((const f32x4*)(ea + (size_t)grow * 64 + c4));
            if (MODE == 1 && c4 == 0) coltile[e] = colidx[grow];
          } else {
            v = *(const f32x4*)(sums_in + (size_t)grow * 64 + c4);
            if (cnt) {
              const float inv = 1.0f / fmaxf(cnt[grow], 1.0f);
              v *= inv;
            }
          }
        } else {
          if (MODE <= 1) {
            if (c4 < 64) {
              const int r = rowidx[grow];
              v = *(const f32x4*)(x + (size_t)r * 64 + c4);
            } else {
              v = __builtin_nontemporal_load((const f32x4*)(ea + (size_t)grow * 64 + (c4 - 64)));
            }
            if (MODE == 1 && c4 == 0) coltile[e] = colidx[grow];
          } else {
            if (c4 < 64) {
              v = *(const f32x4*)(x + (size_t)grow * 64 + c4);
            } else {
              v = *(const f32x4*)(sums_in + (size_t)grow * 64 + (c4 - 64));
              if (cnt) {
                const float inv = 1.0f / fmaxf(cnt[grow], 1.0f);
                v *= inv;
              }
            }
          }
        }
      }
      pack4(&Albs[e * KP + c4], v);
    }
    __syncthreads();

    floatx4 acc[4];
#pragma unroll
    for (int nt = 0; nt < 4; ++nt) acc[nt] = (floatx4){0.f, 0.f, 0.f, 0.f};
    const ushort* arow = &Albs[(wv * 16 + m) * KP];
#pragma unroll
    for (int kc = 0; kc < KC / 32; ++kc) {
      const short8 af = *(const short8*)(arow + kc * 32 + quad * 8);
#pragma unroll
      for (int nt = 0; nt < 4; ++nt) {
        short8 bfr;
        if constexpr (USEP) {
          bfr = breg[kc][nt];
        } else {
          bfr = *(const short8*)(&Btl[(nt * 16 + m) * KP + kc * 32 + quad * 8]);
        }
        acc[nt] = __builtin_amdgcn_mfma_f32_16x16x32_bf16(af, bfr, acc[nt], 0, 0, 0);
      }
    }

    const int lr0 = wv * 16 + quad * 4;
#pragma unroll
    for (int nt = 0; nt < 4; ++nt) {
      const int c = nt * 16 + m;
      const float bb = USEP ? 0.f : biasl[c];
      if (MODE == 0 || MODE == 2) {
        float s = 0.f, q = 0.f;
#pragma unroll
        for (int r = 0; r < 4; ++r) {
          const int grow = base + lr0 + r;
          if (grow < nrows) {
            const float v = acc[nt][r] + (USEP ? pv[nt][r] : bb);
            s += v;
            q += v * v;
          }
        }
        s += __shfl_xor(s, 16); s += __shfl_xor(s, 32);
        q += __shfl_xor(q, 16); q += __shfl_xor(q, 32);
        if (quad == 0) { wsum[wv][c] += s; wsq[wv][c] += q; }
      } else {
        const float sc = scl[c];
        const float sh = scl[64 + c];
#pragma unroll
        for (int r = 0; r < 4; ++r) {
          const int e = lr0 + r;
          const int grow = base + e;
          if (grow < nrows) {
            const float h = acc[nt][r] + (USEP ? pv[nt][r] : bb);
            const float o = silu(h * sc + sh);
            if (MODE == 1) {
              unsafeAtomicAdd(&sums_out[(size_t)coltile[e] * 64 + c], o);
            } else {
              __builtin_nontemporal_store(o, &out[(size_t)grow * 64 + c]);
            }
          }
        }
        if (MODE == 1 && nt == 0 && m == 0) {
#pragma unroll
          for (int r = 0; r < 4; ++r) {
            const int e = lr0 + r;
            if (base + e < nrows) unsafeAtomicAdd(&cnt_out[coltile[e]], 1.0f);
          }
        }
      }
    }
  }

  if (MODE == 0 || MODE == 2) {
    __syncthreads();
    if (tid < 128) {
      const int c = tid & 63;
      if (tid < 64) {
        unsafeAtomicAdd(&ssum[c], wsum[0][c] + wsum[1][c] + wsum[2][c] + wsum[3][c]);
      } else {
        unsafeAtomicAdd(&ssq[c], wsq[0][c] + wsq[1][c] + wsq[2][c] + wsq[3][c]);
      }
    }
  }
}

__global__ void finalize_stats(const float* __restrict__ ss, const float* __restrict__ sq,
                               const float* __restrict__ g, const float* __restrict__ be,
                               float* __restrict__ scsh, float invn) {
  const int c = threadIdx.x;  // 64 threads
  const float mu  = ss[c] * invn;
  const float var = sq[c] * invn - mu * mu;
  const float rs  = rsqrtf(fmaxf(var, 0.0f) + EPS);
  const float s   = g[c] * rs;
  scsh[c]      = s;
  scsh[64 + c] = be[c] - mu * s;
}

extern "C" void kernel_launch(void* const* d_in, const int* in_sizes, int n_in,
                              void* d_out, int out_size, void* d_ws, size_t ws_size,
                              hipStream_t stream) {
  const int N = in_sizes[0] / 64;
  const int E = in_sizes[1] / 64;
  const float* x   = (const float*)d_in[0];
  const float* ea  = (const float*)d_in[1];
  const float* W1  = (const float*)d_in[3];
  const float* b1  = (const float*)d_in[4];
  const float* g1  = (const float*)d_in[5];
  const float* be1 = (const float*)d_in[6];
  const float* W2  = (const float*)d_in[7];
  const float* b2  = (const float*)d_in[8];
  const float* g2  = (const float*)d_in[9];
  const float* be2 = (const float*)d_in[10];
  const int* ei   = (const int*)d_in[11];  // [2,E] int32
  const int* row  = ei;
  const int* colv = ei + E;

  const int ntE = (E + 63) / 64;
  const int ntN = (N + 63) / 64;
  const int gE  = ntE < 2048 ? ntE : 2048;
  const int gN  = ntN < 2048 ? ntN : 2048;
  const int nb  = (N + 2047) / 2048;

  // Top-path layout (words):
  //   sums/agg 64N | cntf N | statE 128 | statN 128 | scsh1 128 | scsh2 128 |
  //   hist N | curs N | bsum 2048 | [16B] P1 32N | [16B] h1s 32E | [16B] P2 32N (opt)
  const size_t need1 = (size_t)4 * (67 * (size_t)N + 2560) + 128 * (size_t)N +
                       128 * (size_t)E + 48;
  const size_t need2 = need1 + 128 * (size_t)N + 16;
  const size_t needSort = ((size_t)N * 99 + (size_t)E + 2560 + 512) * sizeof(float);
  const size_t needP    = ((size_t)N * 97 + 512) * sizeof(float);

  if (ws_size >= need1) {
    const bool twoP = (ws_size >= need2);
    float* sums  = (float*)d_ws;            // "agg" (mean) in top path
    float* cntf  = sums + (size_t)N * 64;
    float* statE = cntf + N;
    float* statN = statE + 128;
    float* scsh1 = statN + 128;             // unused in top path (kept for layout)
    float* scsh2 = scsh1 + 128;
    int*   hist  = (int*)(scsh2 + 128);
    int*   curs  = hist + N;
    int*   bsum  = curs + N;
    ushort* P1 = (ushort*)(((uintptr_t)(bsum + 2048) + 15) & ~(uintptr_t)15);
    ushort* h1s = (ushort*)(((uintptr_t)(P1 + (size_t)N * 64) + 15) & ~(uintptr_t)15);
    ushort* P2 = twoP
        ? (ushort*)(((uintptr_t)(h1s + (size_t)E * 64) + 15) & ~(uintptr_t)15)
        : nullptr;

    // statE..scsh2 (512 floats) + hist (N ints) contiguous
    hipMemsetAsync(statE, 0, (512 + (size_t)N) * sizeof(float), stream);

    k_hist<<<dim3(1024), dim3(256), 0, stream>>>(colv, hist, E);
    k_scanA<<<dim3(nb), dim3(256), 0, stream>>>(hist, bsum, N);
    k_scanC2<<<dim3(nb), dim3(256), 0, stream>>>(hist, bsum, nb, curs, cntf, N);

    precompute_P12<<<dim3(gN), dim3(256), 0, stream>>>(x, W1, b1, W2, b2, P1, P2, N, ntN);
    edge_pass0_v2<<<dim3(gE), dim3(256), 0, stream>>>(
        ea, row, colv, curs, W1, P1, h1s, statE, statE + 64, E, ntE);
    {
      const int nwalk = (N + 1) / 2;
      const int segblocks = (nwalk * 8 + 255) / 256;
      seg_reduce_v2<<<dim3(segblocks), dim3(256), 0, stream>>>(
          h1s, hist, curs, statE, g1, be1, sums, N, 1.0f / (float)E);
    }
    if (!twoP) {
      // reuse P1 buffer for P2 (P1's last consumer was pass0)
      precompute_P12<<<dim3(gN), dim3(256), 0, stream>>>(x, W2, b2, nullptr, nullptr,
                                                         P1, nullptr, N, ntN);
      P2 = P1;
    }
    fused_gemm<2, 1><<<dim3(gN), dim3(256), 0, stream>>>(
        x, nullptr, sums, nullptr, nullptr, nullptr, W2, b2, nullptr, P2,
        statN, statN + 64, nullptr, nullptr, nullptr, nullptr, 0,
        nullptr, nullptr, nullptr, 0.f, N, ntN);
    fused_gemm<3, 1><<<dim3(gN), dim3(256), 0, stream>>>(
        x, nullptr, sums, nullptr, nullptr, nullptr, W2, b2, nullptr, P2,
        nullptr, nullptr, nullptr, nullptr, (float*)d_out, nullptr, 0,
        statN, g2, be2, 1.0f / (float)N, N, ntN);
    return;
  }

  if (ws_size >= needSort) {
    float* sums  = (float*)d_ws;
    float* cntf  = sums + (size_t)N * 64;
    float* statE = cntf + N;
    float* statN = statE + 128;
    float* scsh1 = statN + 128;
    float* scsh2 = scsh1 + 128;
    int*   hist  = (int*)(scsh2 + 128);
    int*   curs  = hist + N;
    int*   bsum  = curs + N;
    int*   perm  = bsum + 2048;
    ushort* Pbf  = (ushort*)(perm + E);

    hipMemsetAsync(statE, 0, (512 + (size_t)N) * sizeof(float), stream);

    k_hist<<<dim3(1024), dim3(256), 0, stream>>>(colv, hist, E);
    k_scanA<<<dim3(nb), dim3(256), 0, stream>>>(hist, bsum, N);
    k_scanC2<<<dim3(nb), dim3(256), 0, stream>>>(hist, bsum, nb, curs, cntf, N);
    k_scatter<<<dim3(1024), dim3(256), 0, stream>>>(colv, curs, perm, E);

    precompute_P12<<<dim3(gN), dim3(256), 0, stream>>>(x, W1, b1, nullptr, nullptr,
                                                       Pbf, nullptr, N, ntN);
    fused_gemm<0, 1><<<dim3(gE), dim3(256), 0, stream>>>(
        x, ea, nullptr, nullptr, row, nullptr, W1, b1, nullptr, Pbf,
        statE, statE + 64, nullptr, nullptr, nullptr, sums, N * 64,
        nullptr, nullptr, nullptr, 0.f, E, ntE);
    finalize_stats<<<dim3(1), dim3(64), 0, stream>>>(statE, statE + 64, g1, be1, scsh1,
                                                     1.0f / (float)E);
    edge_pass1_sorted<<<dim3(gE), dim3(256), 0, stream>>>(
        ea, row, colv, perm, W1, scsh1, Pbf, sums, E, ntE);
    precompute_P12<<<dim3(gN), dim3(256), 0, stream>>>(x, W2, b2, nullptr, nullptr,
                                                       Pbf, nullptr, N, ntN);
    fused_gemm<2, 1><<<dim3(gN), dim3(256), 0, stream>>>(
        x, nullptr, sums, cntf, nullptr, nullptr, W2, b2, nullptr, Pbf,
        statN, statN + 64, nullptr, nullptr, nullptr, nullptr, 0,
        nullptr, nullptr, nullptr, 0.f, N, ntN);
    finalize_stats<<<dim3(1), dim3(64), 0, stream>>>(statN, statN + 64, g2, be2, scsh2,
                                                     1.0f / (float)N);
    fused_gemm<3, 1><<<dim3(gN), dim3(256), 0, stream>>>(
        x, nullptr, sums, cntf, nullptr, nullptr, W2, b2, scsh2, Pbf,
        nullptr, nullptr, nullptr, nullptr, (float*)d_out, nullptr, 0,
        nullptr, nullptr, nullptr, 0.f, N, ntN);
    return;
  }

  // -------- legacy fallbacks --------
  float* sums  = (float*)d_ws;
  float* cnt   = sums + (size_t)N * 64;
  float* statE = cnt + N;
  float* statN = statE + 128;
  float* scsh1 = statN + 128;
  float* scsh2 = scsh1 + 128;
  ushort* Pbf  = (ushort*)(scsh2 + 128);
  const bool useP = (ws_size >= needP);
  const int zn = N * 65;

  hipMemsetAsync(statE, 0, 512 * sizeof(float), stream);

  if (useP) {
    precompute_P12<<<dim3(gN), dim3(256), 0, stream>>>(x, W1, b1, nullptr, nullptr,
                                                       Pbf, nullptr, N, ntN);
    fused_gemm<0, 1><<<dim3(gE), dim3(256), 0, stream>>>(
        x, ea, nullptr, nullptr, row, nullptr, W1, b1, nullptr, Pbf,
        statE, statE + 64, nullptr, nullptr, nullptr, sums, zn,
        nullptr, nullptr, nullptr, 0.f, E, ntE);
    finalize_stats<<<dim3(1), dim3(64), 0, stream>>>(statE, statE + 64, g1, be1, scsh1,
                                                     1.0f / (float)E);
    fused_gemm<1, 1><<<dim3(gE), dim3(256), 0, stream>>>(
        x, ea, nullptr, nullptr, row, colv, W1, b1, scsh1, Pbf,
        nullptr, nullptr, sums, cnt, nullptr, nullptr, 0,
        nullptr, nullptr, nullptr, 0.f, E, ntE);
    precompute_P12<<<dim3(gN), dim3(256), 0, stream>>>(x, W2, b2, nullptr, nullptr,
                                                       Pbf, nullptr, N, ntN);
    fused_gemm<2, 1><<<dim3(gN), dim3(256), 0, stream>>>(
        x, nullptr, sums, cnt, nullptr, nullptr, W2, b2, nullptr, Pbf,
        statN, statN + 64, nullptr, nullptr, nullptr, nullptr, 0,
        nullptr, nullptr, nullptr, 0.f, N, ntN);
    finalize_stats<<<dim3(1), dim3(64), 0, stream>>>(statN, statN + 64, g2, be2, scsh2,
                                                     1.0f / (float)N);
    fused_gemm<3, 1><<<dim3(gN), dim3(256), 0, stream>>>(
        x, nullptr, sums, cnt, nullptr, nullptr, W2, b2, scsh2, Pbf,
        nullptr, nullptr, nullptr, nullptr, (float*)d_out, nullptr, 0,
        nullptr, nullptr, nullptr, 0.f, N, ntN);
  } else {
    fused_gemm<0, 0><<<dim3(gE), dim3(256), 0, stream>>>(
        x, ea, nullptr, nullptr, row, nullptr, W1, b1, nullptr, nullptr,
        statE, statE + 64, nullptr, nullptr, nullptr, sums, zn,
        nullptr, nullptr, nullptr, 0.f, E, ntE);
    finalize_stats<<<dim3(1), dim3(64), 0, stream>>>(statE, statE + 64, g1, be1, scsh1,
                                                     1.0f / (float)E);
    fused_gemm<1, 0><<<dim3(gE), dim3(256), 0, stream>>>(
        x, ea, nullptr, nullptr, row, colv, W1, b1, scsh1, nullptr,
        nullptr, nullptr, sums, cnt, nullptr, nullptr, 0,
        nullptr, nullptr, nullptr, 0.f, E, ntE);
    fused_gemm<2, 0><<<dim3(gN), dim3(256), 0, stream>>>(
        x, nullptr, sums, cnt, nullptr, nullptr, W2, b2, nullptr, nullptr,
        statN, statN + 64, nullptr, nullptr, nullptr, nullptr, 0,
        nullptr, nullptr, nullptr, 0.f, N, ntN);
    finalize_stats<<<dim3(1), dim3(64), 0, stream>>>(statN, statN + 64, g2, be2, scsh2,
                                                     1.0f / (float)N);
    fused_gemm<3, 0><<<dim3(gN), dim3(256), 0, stream>>>(
        x, nullptr, sums, cnt, nullptr, nullptr, W2, b2, scsh2, nullptr,
        nullptr, nullptr, nullptr, nullptr, (float*)d_out, nullptr, 0,
        nullptr, nullptr, nullptr, 0.f, N, ntN);
  }
}